// Round 3
// baseline (266.130 us; speedup 1.0000x reference)
//
#include <hip/hip_runtime.h>
#include <math.h>

#define D 256
#define H 8
#define HD 32
#define S 255
#define S1 256
#define B 4

// Workspace layout (float offsets)
#define WS_Q      0          // (unused storage, kept for layout)
#define WS_K      262144
#define WS_V      524288     // [B*S1][256]
#define WS_AP     786432     // [B*S][256] A' = desc@W1a.T + eb1
#define WS_BP     1048576    // [B*S][256] B'
#define WS_BT     1310720    // [B][256 k][256 j]  B'^T (col 255 = 0)
#define WS_CT     1572864    // [B][256 k][256 j]  (A'+B')^T
#define WS_G      1835008    // [B][256][256]  G[i][j] = A'[i]·B'[j]
#define WS_MT     2097152    // [256 k][8 h]
#define WS_CH     2099200    // [8]
#define WS_QLOG   2099264    // [B][H][256]   (atomic accum, memset 0)
#define WS_KLOG   2107456    // [B][H][256]
#define WS_SA     2115648    // [B][256]
#define WS_QA     2116672
#define WS_SB     2117696
#define WS_QB     2118720
#define WS_ZERO   2119744    // 256 zeros
// memset region: WS_QLOG .. WS_ZERO+256  (20736 floats)

// ---------------------------------------------------------------------------
// 64x64 fp32 tile GEMM, 512 threads, with fused epilogues.
// mode: 0 plain store | 1 qlog-atomics (no store) | 2 klog-atomics (no store)
//       3 store+statsA | 4 store+statsB
// ---------------------------------------------------------------------------
__device__ __forceinline__ void gemm_tile(
    const float* __restrict__ X, int xRows,
    const float* __restrict__ W, int wStride, int wOff, int wRows,
    const float* __restrict__ bias,
    float* __restrict__ out, int oStride, int oRows, int oCols,
    int mBase, int nBase, int mode,
    float* __restrict__ ws, const float* __restrict__ aW)
{
    __shared__ float Xst[32][68];
    __shared__ float Wst[32][68];
    int tid = threadIdx.x;
    int r  = tid >> 3;
    int kq = tid & 7;
    int tm = tid >> 4;      // 0..31 -> rows tm*2+{0,1}
    int tn = tid & 15;      // 0..15 -> cols tn*4+{0..3}
    float acc[2][4] = {};
    for (int k0 = 0; k0 < 256; k0 += 32) {
        __syncthreads();
        float4 xv = make_float4(0.f,0.f,0.f,0.f);
        float4 wv = make_float4(0.f,0.f,0.f,0.f);
        int xr = mBase + r;
        if (xr < xRows) xv = *(const float4*)&X[xr*256 + k0 + kq*4];
        int wr = nBase + r;
        if (wr < wRows) wv = *(const float4*)&W[wr*wStride + wOff + k0 + kq*4];
        Xst[kq*4+0][r] = xv.x; Xst[kq*4+1][r] = xv.y;
        Xst[kq*4+2][r] = xv.z; Xst[kq*4+3][r] = xv.w;
        Wst[kq*4+0][r] = wv.x; Wst[kq*4+1][r] = wv.y;
        Wst[kq*4+2][r] = wv.z; Wst[kq*4+3][r] = wv.w;
        __syncthreads();
        #pragma unroll 8
        for (int kk = 0; kk < 32; kk++) {
            float2 a2 = *(const float2*)&Xst[kk][tm*2];
            float4 b4 = *(const float4*)&Wst[kk][tn*4];
            acc[0][0] = fmaf(a2.x, b4.x, acc[0][0]);
            acc[0][1] = fmaf(a2.x, b4.y, acc[0][1]);
            acc[0][2] = fmaf(a2.x, b4.z, acc[0][2]);
            acc[0][3] = fmaf(a2.x, b4.w, acc[0][3]);
            acc[1][0] = fmaf(a2.y, b4.x, acc[1][0]);
            acc[1][1] = fmaf(a2.y, b4.y, acc[1][1]);
            acc[1][2] = fmaf(a2.y, b4.z, acc[1][2]);
            acc[1][3] = fmaf(a2.y, b4.w, acc[1][3]);
        }
    }
    int cbase = nBase + tn*4;
    float4 bv = make_float4(0.f,0.f,0.f,0.f);
    if (bias && cbase < oCols) bv = *(const float4*)&bias[cbase];
    #pragma unroll
    for (int x = 0; x < 2; x++) {
        int rr = mBase + tm*2 + x;
        if (rr >= oRows) continue;
        float o0 = acc[x][0] + bv.x;
        float o1 = acc[x][1] + bv.y;
        float o2 = acc[x][2] + bv.z;
        float o3 = acc[x][3] + bv.w;
        if (mode == 1 || mode == 2) {
            // partial dot with aW (wq or wk) -> atomic into qlog/klog
            const float* a = aW + ((mode == 1) ? 0 : 32);
            int d0 = cbase & 31;
            float val = o0*a[d0] + o1*a[d0+1] + o2*a[d0+2] + o3*a[d0+3];
            int h  = (cbase >> 5) & 7;
            int bb = rr >> 8, tt = rr & 255;
            float* lg = ws + ((mode == 1) ? WS_QLOG : WS_KLOG);
            atomicAdd(&lg[(bb*8 + h)*256 + tt], val);
        } else {
            if (cbase + 3 < oCols) {
                float4 o = make_float4(o0, o1, o2, o3);
                *(float4*)&out[rr*oStride + cbase] = o;
            } else {
                float oo[4] = {o0, o1, o2, o3};
                for (int y = 0; y < 4; y++)
                    if (cbase + y < oCols) out[rr*oStride + cbase + y] = oo[y];
            }
            if (mode >= 3) {
                float s = o0 + o1 + o2 + o3;
                float q = o0*o0 + o1*o1 + o2*o2 + o3*o3;
                int bb = rr / S;
                int jj = rr - bb*S;
                float* Sp = ws + ((mode == 3) ? WS_SA : WS_SB);
                float* Qp = ws + ((mode == 3) ? WS_QA : WS_QB);
                atomicAdd(&Sp[bb*256 + jj], s);
                atomicAdd(&Qp[bb*256 + jj], q);
            }
        }
    }
}

// ---------------------------------------------------------------------------
// Kernel 1: z=0 q-logits | 1 k-logits | 2 V | 3 A'+statsA | 4 B'+statsB
//           z=5 (block 0,0 only): Mt + ch
// grid (16,4,6) x 512
// ---------------------------------------------------------------------------
__global__ __launch_bounds__(512, 4) void k1_gemms(
    const float* __restrict__ desc, const float* __restrict__ nve,
    const float* __restrict__ qW, const float* __restrict__ qb,
    const float* __restrict__ kW, const float* __restrict__ kb,
    const float* __restrict__ vW, const float* __restrict__ vb,
    const float* __restrict__ eW1, const float* __restrict__ eb1,
    const float* __restrict__ eW2, const float* __restrict__ eb2,
    const float* __restrict__ aW, float* __restrict__ ws)
{
    int z = blockIdx.z;
    if (z == 5) {
        if (blockIdx.x != 0 || blockIdx.y != 0) return;
        int tid = threadIdx.x;
        if (tid < 256) {
            #pragma unroll
            for (int h = 0; h < 8; h++) {
                float acc = 0.f;
                #pragma unroll
                for (int hd = 0; hd < 32; hd++)
                    acc = fmaf(aW[64+hd], eW2[(h*32+hd)*256 + tid], acc);
                ws[WS_MT + tid*8 + h] = acc;
            }
            if (tid == 0) {
                #pragma unroll
                for (int h = 0; h < 8; h++) {
                    float c = 0.f;
                    for (int hd = 0; hd < 32; hd++)
                        c = fmaf(aW[64+hd], eb2[h*32+hd], c);
                    ws[WS_CH + h] = c;
                }
            }
        }
        return;
    }
    const float *X, *W, *bias; float* out; int xRows, wStride, wOff, mode;
    switch (z) {
      case 0: X=nve;  W=qW;  bias=qb;      out=ws+WS_Q;  xRows=1024; wStride=256; wOff=0;   mode=1; break;
      case 1: X=nve;  W=kW;  bias=kb;      out=ws+WS_K;  xRows=1024; wStride=256; wOff=0;   mode=2; break;
      case 2: X=nve;  W=vW;  bias=vb;      out=ws+WS_V;  xRows=1024; wStride=256; wOff=0;   mode=0; break;
      case 3: X=desc; W=eW1; bias=eb1;     out=ws+WS_AP; xRows=1020; wStride=512; wOff=0;   mode=3; break;
      default:X=desc; W=eW1; bias=nullptr; out=ws+WS_BP; xRows=1020; wStride=512; wOff=256; mode=4; break;
    }
    gemm_tile(X, xRows, W, wStride, wOff, 256, bias,
              out, 256, xRows, 256, blockIdx.x*64, blockIdx.y*64, mode, ws, aW);
}

// ---------------------------------------------------------------------------
// Kernel 2: z<4: transpose/combine (b=z) | z>=4: G gemm (b=z-4, x<4,y<4)
// grid (8,8,8) x 512
// ---------------------------------------------------------------------------
__global__ __launch_bounds__(512, 4) void k2_mid(float* __restrict__ ws)
{
    int z = blockIdx.z;
    int tid = threadIdx.x;
    if (z < 4) {
        __shared__ float tA[32][33], tB[32][33];
        int b = z;
        int j0 = blockIdx.x * 32;
        int k0 = blockIdx.y * 32;
        int lr = tid >> 5;    // 0..15
        int lc = tid & 31;
        #pragma unroll
        for (int t = 0; t < 2; t++) {
            int jj = lr + t*16;
            int j = j0 + jj;
            float av = 0.f, bv = 0.f;
            if (j < S) {
                av = ws[WS_AP + (b*S + j)*256 + k0 + lc];
                bv = ws[WS_BP + (b*S + j)*256 + k0 + lc];
            }
            tA[jj][lc] = av;
            tB[jj][lc] = bv;
        }
        __syncthreads();
        #pragma unroll
        for (int t = 0; t < 2; t++) {
            int kk = lr + t*16;
            int k = k0 + kk;
            int j = j0 + lc;
            float av = tA[lc][kk];
            float bv = tB[lc][kk];
            ws[WS_BT + (b*256 + k)*256 + j] = bv;
            ws[WS_CT + (b*256 + k)*256 + j] = av + bv;
        }
    } else {
        int b = z - 4;
        if (blockIdx.x < 4 && blockIdx.y < 4) {
            gemm_tile(ws + WS_AP + b*S*256, 255,
                      ws + WS_BP + b*S*256, 256, 0, 255,
                      nullptr,
                      ws + WS_G + b*65536, 256, 255, 255,
                      blockIdx.x*64, blockIdx.y*64, 0, ws, nullptr);
        }
    }
}

// ---------------------------------------------------------------------------
// Kernel 3: main.  block=(i,b), 512 threads, half=tid>>8 splits the k loop.
// All per-k uniforms (A' row, ln_g, ln_b, M rows) read via scalar loads.
// ---------------------------------------------------------------------------
__global__ __launch_bounds__(512, 8) void main_kernel(
    const float* __restrict__ ln_g, const float* __restrict__ ln_b,
    const float* __restrict__ ab, const float* __restrict__ ws,
    float* __restrict__ out)
{
    int b = blockIdx.y;
    int i = blockIdx.x;
    int tid = threadIdx.x;
    int j = tid & 255;
    int half = tid >> 8;
    int m = j - 1;

    __shared__ float PL[8][256];
    __shared__ float part[256][8];
    __shared__ float cpart[512];
    __shared__ float mx[8], sm[8];

    const float* colBase = ws + ((i >= 1) ? WS_BT : WS_CT) + b*65536;
    const float* Arow = (i >= 1) ? (ws + WS_AP + (b*S + (i-1))*256)
                                 : (ws + WS_ZERO);
    float acc[8] = {0,0,0,0,0,0,0,0};

    if (j >= 1) {
        float sa, qa, sb, qb, g;
        if (i >= 1) {
            int ii = i - 1;
            sa = ws[WS_SA + b*256 + ii]; qa = ws[WS_QA + b*256 + ii];
            sb = ws[WS_SB + b*256 + m];  qb = ws[WS_QB + b*256 + m];
            g  = ws[WS_G + (b*256 + ii)*256 + m];
        } else {
            sa = ws[WS_SA + b*256 + m];  qa = ws[WS_QA + b*256 + m];
            sb = ws[WS_SB + b*256 + m];  qb = ws[WS_QB + b*256 + m];
            g  = ws[WS_G + (b*256 + m)*256 + m];
        }
        float s1v = sa + sb;
        float s2v = qa + qb + 2.f*g;
        float mu  = s1v * (1.0f/256.0f);
        float var = s2v * (1.0f/256.0f) - mu*mu;
        float inv = rsqrtf(var + 1e-5f);
        float mus = mu * inv;
        const float* cp = colBase + m;
        const float* Mbase = ws + WS_MT;
        int kb = half * 128;
        #pragma unroll 4
        for (int kk = 0; kk < 128; kk++) {
            int k = kb + kk;
            float a  = Arow[k];       // s_load (uniform)
            float g1 = ln_g[k];       // s_load
            float b1 = ln_b[k];       // s_load
            float t0 = cp[(size_t)k*256] + a;   // only vector load
            float zz = fmaf(t0, inv, -mus);
            float w  = fmaxf(fmaf(zz, g1, b1), 0.f);
            const float* Mr = Mbase + k*8;      // s_load x8 (uniform)
            acc[0] = fmaf(w, Mr[0], acc[0]);
            acc[1] = fmaf(w, Mr[1], acc[1]);
            acc[2] = fmaf(w, Mr[2], acc[2]);
            acc[3] = fmaf(w, Mr[3], acc[3]);
            acc[4] = fmaf(w, Mr[4], acc[4]);
            acc[5] = fmaf(w, Mr[5], acc[5]);
            acc[6] = fmaf(w, Mr[6], acc[6]);
            acc[7] = fmaf(w, Mr[7], acc[7]);
        }
    }

    if (half == 1) {
        *(float4*)&part[j][0] = make_float4(acc[0], acc[1], acc[2], acc[3]);
        *(float4*)&part[j][4] = make_float4(acc[4], acc[5], acc[6], acc[7]);
    }
    __syncthreads();

    if (half == 0) {
        float abv = ab[0];
        #pragma unroll
        for (int h = 0; h < 8; h++) {
            float base = ws[WS_QLOG + (b*8+h)*256 + i]   // s_load
                       + ws[WS_KLOG + (b*8+h)*256 + j] + abv;
            float l;
            if (j == 0) l = base - 1e9f;
            else        l = base + acc[h] + part[j][h] + ws[WS_CH + h];
            PL[h][j] = l;
        }
    }
    __syncthreads();

    if (tid < 256) {
        int h = tid >> 5, sgl = tid & 31;
        float mval = -INFINITY;
        #pragma unroll
        for (int r = 0; r < 8; r++) mval = fmaxf(mval, PL[h][sgl + r*32]);
        #pragma unroll
        for (int off = 16; off >= 1; off >>= 1)
            mval = fmaxf(mval, __shfl_xor(mval, off, 64));
        if (sgl == 0) mx[h] = mval;
    }
    __syncthreads();

    float p[8];
    if (half == 0) {
        #pragma unroll
        for (int h = 0; h < 8; h++) p[h] = expf(PL[h][j] - mx[h]);
    }
    __syncthreads();
    if (half == 0) {
        #pragma unroll
        for (int h = 0; h < 8; h++) PL[h][j] = p[h];
    }
    __syncthreads();

    if (tid < 256) {
        int h = tid >> 5, sgl = tid & 31;
        float sv = 0.f;
        #pragma unroll
        for (int r = 0; r < 8; r++) sv += PL[h][sgl + r*32];
        #pragma unroll
        for (int off = 16; off >= 1; off >>= 1)
            sv += __shfl_xor(sv, off, 64);
        if (sgl == 0) sm[h] = sv;
    }
    __syncthreads();

    if (half == 0) {
        float* attnOut = out + B*S1*D;
        #pragma unroll
        for (int h = 0; h < 8; h++)
            attnOut[((b*8+h)*256 + i)*256 + j] = p[h] / sm[h];
    }

    // ctx: output col = j; jj-range split across halves; PL read as float4
    {
        int col = j;
        int h = col >> 5;
        const float* v = ws + WS_V + b*65536;
        int jb = half * 128;
        float c0 = 0.f;
        #pragma unroll 4
        for (int t = 0; t < 128; t += 4) {
            float4 pv = *(const float4*)&PL[h][jb + t];
            c0 = fmaf(pv.x, v[(jb + t    )*256 + col], c0);
            c0 = fmaf(pv.y, v[(jb + t + 1)*256 + col], c0);
            c0 = fmaf(pv.z, v[(jb + t + 2)*256 + col], c0);
            c0 = fmaf(pv.w, v[(jb + t + 3)*256 + col], c0);
        }
        cpart[tid] = c0;
    }
    __syncthreads();
    if (half == 0) {
        int h = j >> 5;
        out[(b*256 + i)*256 + j] = (cpart[tid] + cpart[tid + 256]) * (1.0f / sm[h]);
    }
}

// ---------------------------------------------------------------------------
extern "C" void kernel_launch(void* const* d_in, const int* in_sizes, int n_in,
                              void* d_out, int out_size, void* d_ws, size_t ws_size,
                              hipStream_t stream)
{
    const float* desc = (const float*)d_in[0];
    const float* nve  = (const float*)d_in[1];
    const float* qW   = (const float*)d_in[2];
    const float* qb   = (const float*)d_in[3];
    const float* kW   = (const float*)d_in[4];
    const float* kb   = (const float*)d_in[5];
    const float* vW   = (const float*)d_in[6];
    const float* vb   = (const float*)d_in[7];
    const float* eW1  = (const float*)d_in[8];
    const float* eb1  = (const float*)d_in[9];
    const float* ln_g = (const float*)d_in[10];
    const float* ln_b = (const float*)d_in[11];
    const float* eW2  = (const float*)d_in[12];
    const float* eb2  = (const float*)d_in[13];
    const float* aW   = (const float*)d_in[14];
    const float* ab   = (const float*)d_in[15];
    float* ws  = (float*)d_ws;
    float* out = (float*)d_out;

    // zero atomic accumulators (QLOG..QB) + the ZERO row, one contiguous span
    hipMemsetAsync((char*)d_ws + (size_t)WS_QLOG*4, 0,
                   (size_t)(WS_ZERO + 256 - WS_QLOG)*4, stream);

    k1_gemms<<<dim3(16, 4, 6), 512, 0, stream>>>(desc, nve, qW, qb, kW, kb, vW, vb,
                                                 eW1, eb1, eW2, eb2, aW, ws);
    k2_mid  <<<dim3(8, 8, 8), 512, 0, stream>>>(ws);
    main_kernel<<<dim3(256, 4), 512, 0, stream>>>(ln_g, ln_b, ab, ws, out);
}

// Round 4
// 236.960 us; speedup vs baseline: 1.1231x; 1.1231x over previous
//
#include <hip/hip_runtime.h>
#include <math.h>

#define D 256
#define H 8
#define HD 32
#define S 255
#define S1 256
#define B 4

typedef _Float16 half8 __attribute__((ext_vector_type(8)));
typedef float f32x4 __attribute__((ext_vector_type(4)));

// Workspace layout (float offsets)
#define WS_Q      0          // dummy (qkv logits fused, no store)
#define WS_K      262144
#define WS_V      524288     // [B*S1][256]
#define WS_AP     786432     // [B*S][256] A' = desc@W1a.T + eb1
#define WS_BP     1048576    // [B*S][256] B'
#define WS_MF     1310720    // 4096 _Float16 = 2048 floats: M in B-fragment order
#define WS_G      1835008    // [B][256][256]  G[i][j] = A'[i]·B'[j]
#define WS_CH     2099200    // [8]
#define WS_QLOG   2099264    // [B][H][256]   (atomic accum, memset 0)
#define WS_KLOG   2107456    // [B][H][256]
#define WS_SA     2115648    // [B][256]
#define WS_QA     2116672
#define WS_SB     2117696
#define WS_QB     2118720    // ends 2119744

// ---------------------------------------------------------------------------
// 64x64 fp32 tile GEMM, 512 threads, fused epilogues.
// mode: 0 plain store | 1 qlog-atomics | 2 klog-atomics | 3 store+statsA | 4 store+statsB
// ---------------------------------------------------------------------------
__device__ __forceinline__ void gemm_tile(
    const float* __restrict__ X, int xRows,
    const float* __restrict__ W, int wStride, int wOff, int wRows,
    const float* __restrict__ bias,
    float* __restrict__ out, int oStride, int oRows, int oCols,
    int mBase, int nBase, int mode,
    float* __restrict__ ws, const float* __restrict__ aW)
{
    __shared__ float Xst[32][68];
    __shared__ float Wst[32][68];
    int tid = threadIdx.x;
    int r  = tid >> 3;
    int kq = tid & 7;
    int tm = tid >> 4;
    int tn = tid & 15;
    float acc[2][4] = {};
    for (int k0 = 0; k0 < 256; k0 += 32) {
        __syncthreads();
        float4 xv = make_float4(0.f,0.f,0.f,0.f);
        float4 wv = make_float4(0.f,0.f,0.f,0.f);
        int xr = mBase + r;
        if (xr < xRows) xv = *(const float4*)&X[xr*256 + k0 + kq*4];
        int wr = nBase + r;
        if (wr < wRows) wv = *(const float4*)&W[wr*wStride + wOff + k0 + kq*4];
        Xst[kq*4+0][r] = xv.x; Xst[kq*4+1][r] = xv.y;
        Xst[kq*4+2][r] = xv.z; Xst[kq*4+3][r] = xv.w;
        Wst[kq*4+0][r] = wv.x; Wst[kq*4+1][r] = wv.y;
        Wst[kq*4+2][r] = wv.z; Wst[kq*4+3][r] = wv.w;
        __syncthreads();
        #pragma unroll 8
        for (int kk = 0; kk < 32; kk++) {
            float2 a2 = *(const float2*)&Xst[kk][tm*2];
            float4 b4 = *(const float4*)&Wst[kk][tn*4];
            acc[0][0] = fmaf(a2.x, b4.x, acc[0][0]);
            acc[0][1] = fmaf(a2.x, b4.y, acc[0][1]);
            acc[0][2] = fmaf(a2.x, b4.z, acc[0][2]);
            acc[0][3] = fmaf(a2.x, b4.w, acc[0][3]);
            acc[1][0] = fmaf(a2.y, b4.x, acc[1][0]);
            acc[1][1] = fmaf(a2.y, b4.y, acc[1][1]);
            acc[1][2] = fmaf(a2.y, b4.z, acc[1][2]);
            acc[1][3] = fmaf(a2.y, b4.w, acc[1][3]);
        }
    }
    int cbase = nBase + tn*4;
    float4 bv = make_float4(0.f,0.f,0.f,0.f);
    if (bias && cbase < oCols) bv = *(const float4*)&bias[cbase];
    #pragma unroll
    for (int x = 0; x < 2; x++) {
        int rr = mBase + tm*2 + x;
        if (rr >= oRows) continue;
        float o0 = acc[x][0] + bv.x;
        float o1 = acc[x][1] + bv.y;
        float o2 = acc[x][2] + bv.z;
        float o3 = acc[x][3] + bv.w;
        if (mode == 1 || mode == 2) {
            const float* a = aW + ((mode == 1) ? 0 : 32);
            int d0 = cbase & 31;
            float val = o0*a[d0] + o1*a[d0+1] + o2*a[d0+2] + o3*a[d0+3];
            int h  = (cbase >> 5) & 7;
            int bb = rr >> 8, tt = rr & 255;
            float* lg = ws + ((mode == 1) ? WS_QLOG : WS_KLOG);
            atomicAdd(&lg[(bb*8 + h)*256 + tt], val);
        } else {
            if (cbase + 3 < oCols) {
                *(float4*)&out[rr*oStride + cbase] = make_float4(o0, o1, o2, o3);
            } else {
                float oo[4] = {o0, o1, o2, o3};
                for (int y = 0; y < 4; y++)
                    if (cbase + y < oCols) out[rr*oStride + cbase + y] = oo[y];
            }
            if (mode >= 3) {
                float s = o0 + o1 + o2 + o3;
                float q = o0*o0 + o1*o1 + o2*o2 + o3*o3;
                int bb = rr / S;
                int jj = rr - bb*S;
                float* Sp = ws + ((mode == 3) ? WS_SA : WS_SB);
                float* Qp = ws + ((mode == 3) ? WS_QA : WS_QB);
                atomicAdd(&Sp[bb*256 + jj], s);
                atomicAdd(&Qp[bb*256 + jj], q);
            }
        }
    }
}

// ---------------------------------------------------------------------------
// Kernel 1: z=0 q-logits | 1 k-logits | 2 V | 3 A'+statsA | 4 B'+statsB
//           z=5 (block 0,0): M in f16 B-fragment order + ch
// ---------------------------------------------------------------------------
__global__ __launch_bounds__(512, 4) void k1_gemms(
    const float* __restrict__ desc, const float* __restrict__ nve,
    const float* __restrict__ qW, const float* __restrict__ qb,
    const float* __restrict__ kW, const float* __restrict__ kb,
    const float* __restrict__ vW, const float* __restrict__ vb,
    const float* __restrict__ eW1, const float* __restrict__ eb1,
    const float* __restrict__ eW2, const float* __restrict__ eb2,
    const float* __restrict__ aW, float* __restrict__ ws)
{
    int z = blockIdx.z;
    if (z == 5) {
        if (blockIdx.x != 0 || blockIdx.y != 0) return;
        int t = threadIdx.x;             // 0..511
        int ks = t >> 6, lane = t & 63;
        int h = lane & 15, q = lane >> 4;
        _Float16* mf = (_Float16*)(ws + WS_MF);
        #pragma unroll
        for (int jj = 0; jj < 8; jj++) {
            int k = ks*32 + q*8 + jj;
            float acc = 0.f;
            if (h < 8) {
                #pragma unroll
                for (int hd = 0; hd < 32; hd++)
                    acc = fmaf(aW[64+hd], eW2[(h*32+hd)*256 + k], acc);
            }
            mf[(ks*64 + lane)*8 + jj] = (_Float16)acc;
        }
        if (t == 0) {
            #pragma unroll
            for (int hh = 0; hh < 8; hh++) {
                float c = 0.f;
                for (int hd = 0; hd < 32; hd++)
                    c = fmaf(aW[64+hd], eb2[hh*32+hd], c);
                ws[WS_CH + hh] = c;
            }
        }
        return;
    }
    const float *X, *W, *bias; float* out; int xRows, wStride, wOff, mode;
    switch (z) {
      case 0: X=nve;  W=qW;  bias=qb;      out=ws+WS_Q;  xRows=1024; wStride=256; wOff=0;   mode=1; break;
      case 1: X=nve;  W=kW;  bias=kb;      out=ws+WS_K;  xRows=1024; wStride=256; wOff=0;   mode=2; break;
      case 2: X=nve;  W=vW;  bias=vb;      out=ws+WS_V;  xRows=1024; wStride=256; wOff=0;   mode=0; break;
      case 3: X=desc; W=eW1; bias=eb1;     out=ws+WS_AP; xRows=1020; wStride=512; wOff=0;   mode=3; break;
      default:X=desc; W=eW1; bias=nullptr; out=ws+WS_BP; xRows=1020; wStride=512; wOff=256; mode=4; break;
    }
    gemm_tile(X, xRows, W, wStride, wOff, 256, bias,
              out, 256, xRows, 256, blockIdx.x*64, blockIdx.y*64, mode, ws, aW);
}

// ---------------------------------------------------------------------------
// Kernel 2: G = A'·B'^T per batch.  grid (4,4,4)
// ---------------------------------------------------------------------------
__global__ __launch_bounds__(512, 4) void k2_G(float* __restrict__ ws)
{
    int b = blockIdx.z;
    gemm_tile(ws + WS_AP + b*S*256, 255,
              ws + WS_BP + b*S*256, 256, 0, 255,
              nullptr,
              ws + WS_G + b*65536, 256, 255, 255,
              blockIdx.x*64, blockIdx.y*64, 0, ws, nullptr);
}

// ---------------------------------------------------------------------------
// Kernel 3: main — MFMA edge-logit GEMM + softmax + ctx.  block=(i,b), 512 thr.
// ---------------------------------------------------------------------------
__global__ __launch_bounds__(512, 4) void main_kernel(
    const float* __restrict__ ln_g, const float* __restrict__ ln_b,
    const float* __restrict__ ab, const float* __restrict__ ws,
    float* __restrict__ out)
{
    int b = blockIdx.y;
    int i = blockIdx.x;
    int tid = threadIdx.x;

    __shared__ float2 st[256];        // per-j (inv, -mu*inv)
    __shared__ float klds[8][256];
    __shared__ float baseh[8];
    __shared__ float PL[8][256];
    __shared__ float cpart[512];
    __shared__ float mx[8], sm[8];

    // stage klog
    #pragma unroll
    for (int t = 0; t < 4; t++) {
        int e = tid + t*512;
        klds[e >> 8][e & 255] = ws[WS_KLOG + b*2048 + e];
    }
    if (tid < 8)
        baseh[tid] = ws[WS_QLOG + (b*8+tid)*256 + i] + ab[0] + ws[WS_CH + tid];
    // stage per-j stats
    if (tid < 256) {
        int j = tid;
        float2 v = make_float2(0.f, 0.f);
        if (j >= 1) {
            int m = j - 1;
            float sa, qa, sb, qb, g;
            if (i >= 1) {
                int ii = i - 1;
                sa = ws[WS_SA + b*256 + ii]; qa = ws[WS_QA + b*256 + ii];
                sb = ws[WS_SB + b*256 + m];  qb = ws[WS_QB + b*256 + m];
                g  = ws[WS_G + (b*256 + ii)*256 + m];
            } else {
                sa = ws[WS_SA + b*256 + m];  qa = ws[WS_QA + b*256 + m];
                sb = ws[WS_SB + b*256 + m];  qb = ws[WS_QB + b*256 + m];
                g  = ws[WS_G + (b*256 + m)*256 + m];
            }
            float mu  = (sa + sb) * (1.0f/256.0f);
            float var = (qa + qb + 2.f*g) * (1.0f/256.0f) - mu*mu;
            float inv = rsqrtf(var + 1e-5f);
            v = make_float2(inv, -mu*inv);
        }
        st[j] = v;
    }
    __syncthreads();

    int lane = tid & 63, wave = tid >> 6;
    int m16 = lane & 15, quad = lane >> 4;
    const _Float16* MF = (const _Float16*)(ws + WS_MF);
    const float* Bp = ws + WS_BP;
    const float* Ap = ws + WS_AP;

    #pragma unroll
    for (int t = 0; t < 2; t++) {
        int jt = wave*2 + t;
        int ja = jt*16 + m16;              // this lane's A-row (j index)
        int m  = (ja >= 1) ? (ja - 1) : 0;
        float2 si = st[ja];
        const float* rowB = Bp + (b*S + m)*256;
        const float* rowA = Ap + (b*S + ((i >= 1) ? (i-1) : m))*256;
        f32x4 acc = {0.f, 0.f, 0.f, 0.f};
        int kb0 = quad*8;
        #pragma unroll 2
        for (int ks = 0; ks < 8; ks++) {
            int kk = ks*32 + kb0;
            float4 c0 = *(const float4*)&rowB[kk];
            float4 c1 = *(const float4*)&rowB[kk+4];
            float4 a0 = *(const float4*)&rowA[kk];
            float4 a1 = *(const float4*)&rowA[kk+4];
            float4 g0 = *(const float4*)&ln_g[kk];
            float4 g1 = *(const float4*)&ln_g[kk+4];
            float4 e0 = *(const float4*)&ln_b[kk];
            float4 e1 = *(const float4*)&ln_b[kk+4];
            half8 af;
            float w;
            w = fmaf(fmaf(c0.x+a0.x, si.x, si.y), g0.x, e0.x); af[0] = (_Float16)fmaxf(w, 0.f);
            w = fmaf(fmaf(c0.y+a0.y, si.x, si.y), g0.y, e0.y); af[1] = (_Float16)fmaxf(w, 0.f);
            w = fmaf(fmaf(c0.z+a0.z, si.x, si.y), g0.z, e0.z); af[2] = (_Float16)fmaxf(w, 0.f);
            w = fmaf(fmaf(c0.w+a0.w, si.x, si.y), g0.w, e0.w); af[3] = (_Float16)fmaxf(w, 0.f);
            w = fmaf(fmaf(c1.x+a1.x, si.x, si.y), g1.x, e1.x); af[4] = (_Float16)fmaxf(w, 0.f);
            w = fmaf(fmaf(c1.y+a1.y, si.x, si.y), g1.y, e1.y); af[5] = (_Float16)fmaxf(w, 0.f);
            w = fmaf(fmaf(c1.z+a1.z, si.x, si.y), g1.z, e1.z); af[6] = (_Float16)fmaxf(w, 0.f);
            w = fmaf(fmaf(c1.w+a1.w, si.x, si.y), g1.w, e1.w); af[7] = (_Float16)fmaxf(w, 0.f);
            half8 bf = *(const half8*)&MF[(ks*64 + lane)*8];
            acc = __builtin_amdgcn_mfma_f32_16x16x32_f16(af, bf, acc, 0, 0, 0);
        }
        // epilogue: C layout col=lane&15(h), row=(lane>>4)*4+reg
        int h = m16;
        if (h < 8) {
            float basev = baseh[h];
            #pragma unroll
            for (int r = 0; r < 4; r++) {
                int jrow = jt*16 + quad*4 + r;
                float val = basev + klds[h][jrow];
                val += (jrow == 0) ? -1e9f : (float)acc[r];
                PL[h][jrow] = val;
            }
        }
    }
    __syncthreads();

    int j = tid & 255;
    int half = tid >> 8;

    if (tid < 256) {   // max per head
        int h = tid >> 5, sgl = tid & 31;
        float mval = -INFINITY;
        #pragma unroll
        for (int r = 0; r < 8; r++) mval = fmaxf(mval, PL[h][sgl + r*32]);
        #pragma unroll
        for (int off = 16; off >= 1; off >>= 1)
            mval = fmaxf(mval, __shfl_xor(mval, off, 64));
        if (sgl == 0) mx[h] = mval;
    }
    __syncthreads();

    float p[8];
    if (half == 0) {
        #pragma unroll
        for (int h = 0; h < 8; h++) p[h] = expf(PL[h][j] - mx[h]);
    }
    __syncthreads();
    if (half == 0) {
        #pragma unroll
        for (int h = 0; h < 8; h++) PL[h][j] = p[h];
    }
    __syncthreads();

    if (tid < 256) {   // sum per head
        int h = tid >> 5, sgl = tid & 31;
        float sv = 0.f;
        #pragma unroll
        for (int r = 0; r < 8; r++) sv += PL[h][sgl + r*32];
        #pragma unroll
        for (int off = 16; off >= 1; off >>= 1)
            sv += __shfl_xor(sv, off, 64);
        if (sgl == 0) sm[h] = sv;
    }
    __syncthreads();

    if (half == 0) {
        float* attnOut = out + B*S1*D;
        #pragma unroll
        for (int h = 0; h < 8; h++)
            attnOut[((b*8+h)*256 + i)*256 + j] = p[h] / sm[h];
    }

    // ctx
    {
        int col = j;
        int h = col >> 5;
        const float* v = ws + WS_V + b*65536;
        int jb = half * 128;
        float c0 = 0.f;
        #pragma unroll 4
        for (int t = 0; t < 128; t += 4) {
            float4 pv = *(const float4*)&PL[h][jb + t];
            c0 = fmaf(pv.x, v[(jb + t    )*256 + col], c0);
            c0 = fmaf(pv.y, v[(jb + t + 1)*256 + col], c0);
            c0 = fmaf(pv.z, v[(jb + t + 2)*256 + col], c0);
            c0 = fmaf(pv.w, v[(jb + t + 3)*256 + col], c0);
        }
        cpart[tid] = c0;
    }
    __syncthreads();
    if (half == 0) {
        int h = j >> 5;
        out[(b*256 + i)*256 + j] = (cpart[tid] + cpart[tid + 256]) * (1.0f / sm[h]);
    }
}

// ---------------------------------------------------------------------------
extern "C" void kernel_launch(void* const* d_in, const int* in_sizes, int n_in,
                              void* d_out, int out_size, void* d_ws, size_t ws_size,
                              hipStream_t stream)
{
    const float* desc = (const float*)d_in[0];
    const float* nve  = (const float*)d_in[1];
    const float* qW   = (const float*)d_in[2];
    const float* qb   = (const float*)d_in[3];
    const float* kW   = (const float*)d_in[4];
    const float* kb   = (const float*)d_in[5];
    const float* vW   = (const float*)d_in[6];
    const float* vb   = (const float*)d_in[7];
    const float* eW1  = (const float*)d_in[8];
    const float* eb1  = (const float*)d_in[9];
    const float* ln_g = (const float*)d_in[10];
    const float* ln_b = (const float*)d_in[11];
    const float* eW2  = (const float*)d_in[12];
    const float* eb2  = (const float*)d_in[13];
    const float* aW   = (const float*)d_in[14];
    const float* ab   = (const float*)d_in[15];
    float* ws  = (float*)d_ws;
    float* out = (float*)d_out;

    // zero atomic accumulators: QLOG..QB contiguous (20480 floats)
    hipMemsetAsync((char*)d_ws + (size_t)WS_QLOG*4, 0, 20480*4, stream);

    k1_gemms<<<dim3(16, 4, 6), 512, 0, stream>>>(desc, nve, qW, qb, kW, kb, vW, vb,
                                                 eW1, eb1, eW2, eb2, aW, ws);
    k2_G    <<<dim3(4, 4, 4), 512, 0, stream>>>(ws);
    main_kernel<<<dim3(256, 4), 512, 0, stream>>>(ln_g, ln_b, ab, ws, out);
}

// Round 5
// 183.890 us; speedup vs baseline: 1.4472x; 1.2886x over previous
//
#include <hip/hip_runtime.h>
#include <math.h>

#define D 256
#define H 8
#define HD 32
#define S 255
#define S1 256
#define B 4

typedef _Float16 half8 __attribute__((ext_vector_type(8)));
typedef float f32x4 __attribute__((ext_vector_type(4)));

// ---- workspace layout (float offsets) ----
#define WS_NVEF   0        // f16[1024*256]
#define WS_DESCF  131072   // f16[1020*256]
#define WS_VWF    262144   // f16[256*256]
#define WS_EW1F   294912   // f16[256*512]
#define WS_APF    360448   // f16[1020*256]
#define WS_BPF    491520   // f16[1020*256]
#define WS_V      622592   // f32[1024*256]
#define WS_AP     884736   // f32[1020*256]  A' = desc@W1a.T + eb1
#define WS_BP     1146880  // f32[1020*256]  B'
#define WS_CP     1409024  // f32[1020*256]  A'+B'
#define WS_G      1671168  // f32[4][256][256]
#define WS_MF     1933312  // f16 frag-order 4096
#define WS_FOLDF  1935360  // f16 frag-order 4096
#define WS_CONST  1937408  // f32[8] chfull = ch + qbb + kbb
#define WS_QLOG   1937440  // f32[4][8][256]
#define WS_KLOG   1945632
#define WS_SA     1953824  // f32[4][256]
#define WS_QA     1954848
#define WS_SB     1955872
#define WS_QB     1956896  // ends 1957920

// ===========================================================================
// kA: z=0 (y==0): f32->f16 conversions.  z=1 (y==1, x==0): folds, MF, consts
// ===========================================================================
__global__ __launch_bounds__(512) void kA(
    const float* __restrict__ desc, const float* __restrict__ nve,
    const float* __restrict__ qW, const float* __restrict__ qb,
    const float* __restrict__ kW, const float* __restrict__ kb,
    const float* __restrict__ vW, const float* __restrict__ eW1,
    const float* __restrict__ eW2, const float* __restrict__ eb2,
    const float* __restrict__ aW, float* __restrict__ ws)
{
    int tid = threadIdx.x;
    if (blockIdx.y == 0) {
        int idx8 = blockIdx.x * 512 + tid;
        if (idx8 >= 89984) return;
        int e = idx8 * 8;
        const float* src; _Float16* dst;
        if (e < 262144)      { src = nve  + e;          dst = ((_Float16*)(ws + WS_NVEF))  + e; }
        else if (e < 523264) { src = desc + (e-262144); dst = ((_Float16*)(ws + WS_DESCF)) + (e-262144); }
        else if (e < 588800) { src = vW   + (e-523264); dst = ((_Float16*)(ws + WS_VWF))   + (e-523264); }
        else                 { src = eW1  + (e-588800); dst = ((_Float16*)(ws + WS_EW1F))  + (e-588800); }
        float4 x0 = *(const float4*)src;
        float4 x1 = *(const float4*)(src + 4);
        half8 h;
        h[0]=(_Float16)x0.x; h[1]=(_Float16)x0.y; h[2]=(_Float16)x0.z; h[3]=(_Float16)x0.w;
        h[4]=(_Float16)x1.x; h[5]=(_Float16)x1.y; h[6]=(_Float16)x1.z; h[7]=(_Float16)x1.w;
        *(half8*)dst = h;
        return;
    }
    if (blockIdx.x != 0) return;
    // ---- fold matrices ----
    __shared__ float foldL[256][17];
    {
        int d = tid & 255;
        int isK = tid >> 8;
        const float* Wm = isK ? kW : qW;
        const float* av = aW + isK * 32;
        float f[8] = {0,0,0,0,0,0,0,0};
        for (int hd = 0; hd < 32; hd++) {
            float a = av[hd];
            #pragma unroll
            for (int h = 0; h < 8; h++)
                f[h] = fmaf(a, Wm[(h*32+hd)*256 + d], f[h]);
        }
        #pragma unroll
        for (int h = 0; h < 8; h++) foldL[d][isK*8 + h] = f[h];
    }
    __syncthreads();
    {   // FOLDF frag-order store
        int ks = tid >> 6, lane = tid & 63;
        int n = lane & 15, kq = lane >> 4;
        _Float16* ff = (_Float16*)(ws + WS_FOLDF);
        #pragma unroll
        for (int jj = 0; jj < 8; jj++) {
            int k = ks*32 + kq*8 + jj;
            ff[(ks*64 + lane)*8 + jj] = (_Float16)foldL[k][n];
        }
    }
    {   // MF: M[k][h] in f16 B-frag order
        int ks = tid >> 6, lane = tid & 63;
        int h = lane & 15, q = lane >> 4;
        _Float16* mf = (_Float16*)(ws + WS_MF);
        #pragma unroll
        for (int jj = 0; jj < 8; jj++) {
            int k = ks*32 + q*8 + jj;
            float a = 0.f;
            if (h < 8) {
                for (int hd = 0; hd < 32; hd++)
                    a = fmaf(aW[64+hd], eW2[(h*32+hd)*256 + k], a);
            }
            mf[(ks*64 + lane)*8 + jj] = (_Float16)a;
        }
    }
    if (tid == 0) {
        #pragma unroll
        for (int h = 0; h < 8; h++) {
            float c = 0.f;
            for (int hd = 0; hd < 32; hd++) {
                c = fmaf(aW[64+hd], eb2[h*32+hd], c);
                c = fmaf(aW[hd],    qb [h*32+hd], c);
                c = fmaf(aW[32+hd], kb [h*32+hd], c);
            }
            ws[WS_CONST + h] = c;
        }
    }
}

// ===========================================================================
// kB: MFMA GEMMs.  z=0: V | z=1: A'(+stats,f16) | z=2: B'(+stats,f16) |
//     z=3 (y==0): qklog = nveF @ FOLDF   grid (16,4,4) x 256
// ===========================================================================
__global__ __launch_bounds__(256, 4) void kB(
    const float* __restrict__ vb, const float* __restrict__ eb1,
    float* __restrict__ ws)
{
    int z = blockIdx.z;
    int tid = threadIdx.x;
    int wave = tid >> 6, lane = tid & 63;
    int m16 = lane & 15, quad = lane >> 4;
    int sr = tid & 63, sko = (tid >> 6) * 16;

    if (z == 3) {
        if (blockIdx.y != 0) return;
        __shared__ _Float16 Af3[4096];
        const _Float16* Xf = (const _Float16*)(ws + WS_NVEF);
        const _Float16* Ff = (const _Float16*)(ws + WS_FOLDF);
        int mBase = blockIdx.x * 64;
        f32x4 acc = {0.f, 0.f, 0.f, 0.f};
        for (int k0 = 0; k0 < 256; k0 += 64) {
            half8 xa[2];
            #pragma unroll
            for (int hh = 0; hh < 2; hh++)
                xa[hh] = *(const half8*)&Xf[(mBase + sr)*256 + k0 + sko + hh*8];
            __syncthreads();
            #pragma unroll
            for (int hh = 0; hh < 2; hh++) {
                int krel = sko + hh*8;
                int c = krel >> 5, q2 = (krel >> 3) & 3;
                int ld = (sr & 15) + 16*q2, rt = sr >> 4;
                *(half8*)&Af3[((rt*2 + c)*64 + ld)*8] = xa[hh];
            }
            __syncthreads();
            #pragma unroll
            for (int c = 0; c < 2; c++) {
                half8 A = *(const half8*)&Af3[((wave*2 + c)*64 + lane)*8];
                half8 Bv = *(const half8*)&Ff[(((k0 >> 5) + c)*64 + lane)*8];
                acc = __builtin_amdgcn_mfma_f32_16x16x32_f16(A, Bv, acc, 0, 0, 0);
            }
        }
        int rr0 = mBase + wave*16 + quad*4;
        #pragma unroll
        for (int r = 0; r < 4; r++) {
            int rr = rr0 + r;
            int bb = rr >> 8, tt = rr & 255;
            if (m16 < 8) ws[WS_QLOG + (bb*8 + m16)*256 + tt] = acc[r];
            else         ws[WS_KLOG + (bb*8 + m16 - 8)*256 + tt] = acc[r];
        }
        return;
    }

    const _Float16 *Xf, *Wf;
    int M, wpitch, woff;
    if (z == 0)      { Xf = (const _Float16*)(ws+WS_NVEF);  M = 1024; Wf = (const _Float16*)(ws+WS_VWF);  wpitch = 256; woff = 0; }
    else if (z == 1) { Xf = (const _Float16*)(ws+WS_DESCF); M = 1020; Wf = (const _Float16*)(ws+WS_EW1F); wpitch = 512; woff = 0; }
    else             { Xf = (const _Float16*)(ws+WS_DESCF); M = 1020; Wf = (const _Float16*)(ws+WS_EW1F); wpitch = 512; woff = 256; }

    __shared__ _Float16 Af[4096];
    __shared__ _Float16 Bf[4096];
    int mBase = blockIdx.x * 64, nBase = blockIdx.y * 64;
    f32x4 acc[2][2] = {};
    half8 zero8 = {(_Float16)0,(_Float16)0,(_Float16)0,(_Float16)0,(_Float16)0,(_Float16)0,(_Float16)0,(_Float16)0};

    for (int k0 = 0; k0 < 256; k0 += 64) {
        half8 xa[2], wb[2];
        int xr = mBase + sr;
        int wr = nBase + sr;
        #pragma unroll
        for (int hh = 0; hh < 2; hh++) {
            int kk = k0 + sko + hh*8;
            xa[hh] = (xr < M) ? *(const half8*)&Xf[xr*256 + kk] : zero8;
            wb[hh] = *(const half8*)&Wf[wr*wpitch + woff + kk];
        }
        __syncthreads();
        #pragma unroll
        for (int hh = 0; hh < 2; hh++) {
            int krel = sko + hh*8;
            int c = krel >> 5, q2 = (krel >> 3) & 3;
            int ld = (sr & 15) + 16*q2, rt = sr >> 4;
            *(half8*)&Af[((rt*2 + c)*64 + ld)*8] = xa[hh];
            *(half8*)&Bf[((rt*2 + c)*64 + ld)*8] = wb[hh];
        }
        __syncthreads();
        int rt0 = (wave >> 1)*2, ct0 = (wave & 1)*2;
        #pragma unroll
        for (int c = 0; c < 2; c++) {
            half8 A0 = *(const half8*)&Af[(((rt0    )*2 + c)*64 + lane)*8];
            half8 A1 = *(const half8*)&Af[(((rt0 + 1)*2 + c)*64 + lane)*8];
            half8 B0 = *(const half8*)&Bf[(((ct0    )*2 + c)*64 + lane)*8];
            half8 B1 = *(const half8*)&Bf[(((ct0 + 1)*2 + c)*64 + lane)*8];
            acc[0][0] = __builtin_amdgcn_mfma_f32_16x16x32_f16(A0, B0, acc[0][0], 0,0,0);
            acc[0][1] = __builtin_amdgcn_mfma_f32_16x16x32_f16(A0, B1, acc[0][1], 0,0,0);
            acc[1][0] = __builtin_amdgcn_mfma_f32_16x16x32_f16(A1, B0, acc[1][0], 0,0,0);
            acc[1][1] = __builtin_amdgcn_mfma_f32_16x16x32_f16(A1, B1, acc[1][1], 0,0,0);
        }
    }

    int rt0 = (wave >> 1)*2, ct0 = (wave & 1)*2;
    if (z == 0) {
        #pragma unroll
        for (int ci = 0; ci < 2; ci++) {
            int col = nBase + (ct0 + ci)*16 + m16;
            float bvv = vb[col];
            #pragma unroll
            for (int ri = 0; ri < 2; ri++)
                #pragma unroll
                for (int r = 0; r < 4; r++) {
                    int rr = mBase + (rt0 + ri)*16 + quad*4 + r;
                    ws[WS_V + rr*256 + col] = acc[ri][ci][r] + bvv;
                }
        }
    } else {
        float* outF = ws + ((z == 1) ? WS_AP : WS_BP);
        _Float16* outH = (_Float16*)(ws + ((z == 1) ? WS_APF : WS_BPF));
        float* Sp = ws + ((z == 1) ? WS_SA : WS_SB);
        float* Qp = ws + ((z == 1) ? WS_QA : WS_QB);
        float sacc[2][4] = {}, qacc[2][4] = {};
        #pragma unroll
        for (int ci = 0; ci < 2; ci++) {
            int col = nBase + (ct0 + ci)*16 + m16;
            float bvv = (z == 1) ? eb1[col] : 0.f;
            #pragma unroll
            for (int ri = 0; ri < 2; ri++)
                #pragma unroll
                for (int r = 0; r < 4; r++) {
                    int rr = mBase + (rt0 + ri)*16 + quad*4 + r;
                    if (rr < 1020) {
                        float o = acc[ri][ci][r] + bvv;
                        outF[rr*256 + col] = o;
                        outH[rr*256 + col] = (_Float16)o;
                        sacc[ri][r] += o;
                        qacc[ri][r] = fmaf(o, o, qacc[ri][r]);
                    }
                }
        }
        #pragma unroll
        for (int ri = 0; ri < 2; ri++)
            #pragma unroll
            for (int r = 0; r < 4; r++) {
                float s = sacc[ri][r], q = qacc[ri][r];
                #pragma unroll
                for (int d = 1; d < 16; d <<= 1) {
                    s += __shfl_xor(s, d, 64);
                    q += __shfl_xor(q, d, 64);
                }
                sacc[ri][r] = s; qacc[ri][r] = q;
            }
        if (m16 == 0) {
            #pragma unroll
            for (int ri = 0; ri < 2; ri++)
                #pragma unroll
                for (int r = 0; r < 4; r++) {
                    int rr = mBase + (rt0 + ri)*16 + quad*4 + r;
                    if (rr < 1020) {
                        int bb = (rr >= 765) ? 3 : (rr >= 510) ? 2 : (rr >= 255) ? 1 : 0;
                        int jj = rr - bb*255;
                        atomicAdd(&Sp[bb*256 + jj], sacc[ri][r]);
                        atomicAdd(&Qp[bb*256 + jj], qacc[ri][r]);
                    }
                }
        }
    }
}

// ===========================================================================
// kC: z<4: G[b] = A'f16 @ B'f16^T  |  z==4: CP = A'+B'.  grid (4,4,5) x 256
// ===========================================================================
__global__ __launch_bounds__(256, 4) void kC(float* __restrict__ ws)
{
    int z = blockIdx.z;
    int tid = threadIdx.x;
    if (z == 4) {
        const float4* a4 = (const float4*)(ws + WS_AP);
        const float4* b4 = (const float4*)(ws + WS_BP);
        float4* c4 = (float4*)(ws + WS_CP);
        int base = (blockIdx.x*4 + blockIdx.y)*256 + tid;
        #pragma unroll 4
        for (int it = 0; it < 64; it++) {
            int idx = base + it*4096;
            if (idx < 65280) {  // 1020*256/4
                float4 av = a4[idx], bv = b4[idx];
                c4[idx] = make_float4(av.x+bv.x, av.y+bv.y, av.z+bv.z, av.w+bv.w);
            }
        }
        return;
    }
    int b = z;
    const _Float16* Xf = (const _Float16*)(ws + WS_APF) + b*65280;
    const _Float16* Wf = (const _Float16*)(ws + WS_BPF) + b*65280;
    float* out = ws + WS_G + b*65536;
    int wave = tid >> 6, lane = tid & 63;
    int m16 = lane & 15, quad = lane >> 4;
    int sr = tid & 63, sko = (tid >> 6) * 16;
    __shared__ _Float16 Af[4096];
    __shared__ _Float16 Bf[4096];
    int mBase = blockIdx.x * 64, nBase = blockIdx.y * 64;
    f32x4 acc[2][2] = {};
    half8 zero8 = {(_Float16)0,(_Float16)0,(_Float16)0,(_Float16)0,(_Float16)0,(_Float16)0,(_Float16)0,(_Float16)0};
    for (int k0 = 0; k0 < 256; k0 += 64) {
        half8 xa[2], wb[2];
        int xr = mBase + sr;
        int wr = nBase + sr;
        #pragma unroll
        for (int hh = 0; hh < 2; hh++) {
            int kk = k0 + sko + hh*8;
            xa[hh] = (xr < 255) ? *(const half8*)&Xf[xr*256 + kk] : zero8;
            wb[hh] = (wr < 255) ? *(const half8*)&Wf[wr*256 + kk] : zero8;
        }
        __syncthreads();
        #pragma unroll
        for (int hh = 0; hh < 2; hh++) {
            int krel = sko + hh*8;
            int c = krel >> 5, q2 = (krel >> 3) & 3;
            int ld = (sr & 15) + 16*q2, rt = sr >> 4;
            *(half8*)&Af[((rt*2 + c)*64 + ld)*8] = xa[hh];
            *(half8*)&Bf[((rt*2 + c)*64 + ld)*8] = wb[hh];
        }
        __syncthreads();
        int rt0 = (wave >> 1)*2, ct0 = (wave & 1)*2;
        #pragma unroll
        for (int c = 0; c < 2; c++) {
            half8 A0 = *(const half8*)&Af[(((rt0    )*2 + c)*64 + lane)*8];
            half8 A1 = *(const half8*)&Af[(((rt0 + 1)*2 + c)*64 + lane)*8];
            half8 B0 = *(const half8*)&Bf[(((ct0    )*2 + c)*64 + lane)*8];
            half8 B1 = *(const half8*)&Bf[(((ct0 + 1)*2 + c)*64 + lane)*8];
            acc[0][0] = __builtin_amdgcn_mfma_f32_16x16x32_f16(A0, B0, acc[0][0], 0,0,0);
            acc[0][1] = __builtin_amdgcn_mfma_f32_16x16x32_f16(A0, B1, acc[0][1], 0,0,0);
            acc[1][0] = __builtin_amdgcn_mfma_f32_16x16x32_f16(A1, B0, acc[1][0], 0,0,0);
            acc[1][1] = __builtin_amdgcn_mfma_f32_16x16x32_f16(A1, B1, acc[1][1], 0,0,0);
        }
    }
    int rt0 = (wave >> 1)*2, ct0 = (wave & 1)*2;
    #pragma unroll
    for (int ci = 0; ci < 2; ci++) {
        int col = nBase + (ct0 + ci)*16 + m16;
        #pragma unroll
        for (int ri = 0; ri < 2; ri++)
            #pragma unroll
            for (int r = 0; r < 4; r++) {
                int rr = mBase + (rt0 + ri)*16 + quad*4 + r;
                out[rr*256 + col] = acc[ri][ci][r];
            }
    }
}

// ===========================================================================
// kD: main — per (i,b): W-phase MFMA, softmax, ctx.  grid (256,4) x 512
// ===========================================================================
__global__ __launch_bounds__(512, 4) void kD(
    const float* __restrict__ ln_g, const float* __restrict__ ln_b,
    const float* __restrict__ ab, const float* __restrict__ ws,
    float* __restrict__ out)
{
    int b = blockIdx.y;
    int i = blockIdx.x;
    int tid = threadIdx.x;

    __shared__ float2 st[256];
    __shared__ float klds[8][256];
    __shared__ float baseh[8];
    __shared__ float gL[256], bL[256], aL[256];
    __shared__ float PL[8][256];
    __shared__ float cpart[512];
    __shared__ float mx[8], sm[8];

    #pragma unroll
    for (int t = 0; t < 4; t++) {
        int e = tid + t*512;
        klds[e >> 8][e & 255] = ws[WS_KLOG + b*2048 + e];
    }
    if (tid < 8)
        baseh[tid] = ws[WS_QLOG + (b*8+tid)*256 + i] + ab[0] + ws[WS_CONST + tid];
    if (tid < 256) {
        gL[tid] = ln_g[tid];
        bL[tid] = ln_b[tid];
        aL[tid] = (i >= 1) ? ws[WS_AP + (b*S + i - 1)*256 + tid] : 0.f;
        // per-j stats
        int j = tid;
        float2 v = make_float2(0.f, 0.f);
        if (j >= 1) {
            int m = j - 1;
            float sa, qa, sb, qb, g;
            if (i >= 1) {
                int ii = i - 1;
                sa = ws[WS_SA + b*256 + ii]; qa = ws[WS_QA + b*256 + ii];
                sb = ws[WS_SB + b*256 + m];  qb = ws[WS_QB + b*256 + m];
                g  = ws[WS_G + (b*256 + ii)*256 + m];
            } else {
                sa = ws[WS_SA + b*256 + m];  qa = ws[WS_QA + b*256 + m];
                sb = ws[WS_SB + b*256 + m];  qb = ws[WS_QB + b*256 + m];
                g  = ws[WS_G + (b*256 + m)*256 + m];
            }
            float mu  = (sa + sb) * (1.0f/256.0f);
            float var = (qa + qb + 2.f*g) * (1.0f/256.0f) - mu*mu;
            float inv = rsqrtf(var + 1e-5f);
            v = make_float2(inv, -mu*inv);
        }
        st[j] = v;
    }
    __syncthreads();

    int lane = tid & 63, wave = tid >> 6;
    int m16 = lane & 15, quad = lane >> 4;
    const _Float16* MF = (const _Float16*)(ws + WS_MF);
    const float* rowsrc = ws + ((i >= 1) ? WS_BP : WS_CP) + b*S*256;

    int ja0 = wave*32 + m16;
    int ja1 = ja0 + 16;
    int mA = (ja0 >= 1) ? (ja0 - 1) : 0;
    int mB = ja1 - 1;
    float2 s0 = st[ja0], s1 = st[ja1];
    const float* r0 = rowsrc + mA*256;
    const float* r1 = rowsrc + mB*256;
    f32x4 acc0 = {0.f,0.f,0.f,0.f}, acc1 = {0.f,0.f,0.f,0.f};
    int kb0 = quad*8;

    #pragma unroll
    for (int ks = 0; ks < 8; ks++) {
        int k = ks*32 + kb0;
        float4 ga = *(const float4*)&gL[k], gb2 = *(const float4*)&gL[k+4];
        float4 ba = *(const float4*)&bL[k], bb2 = *(const float4*)&bL[k+4];
        float4 aa = *(const float4*)&aL[k], ab2 = *(const float4*)&aL[k+4];
        half8 bf = *(const half8*)&MF[(ks*64 + lane)*8];
        float w;
        {
            float4 c0 = *(const float4*)&r0[k], c1 = *(const float4*)&r0[k+4];
            half8 af;
            w = fmaf(fmaf(c0.x+aa.x,  s0.x, s0.y), ga.x,  ba.x);  af[0] = (_Float16)fmaxf(w, 0.f);
            w = fmaf(fmaf(c0.y+aa.y,  s0.x, s0.y), ga.y,  ba.y);  af[1] = (_Float16)fmaxf(w, 0.f);
            w = fmaf(fmaf(c0.z+aa.z,  s0.x, s0.y), ga.z,  ba.z);  af[2] = (_Float16)fmaxf(w, 0.f);
            w = fmaf(fmaf(c0.w+aa.w,  s0.x, s0.y), ga.w,  ba.w);  af[3] = (_Float16)fmaxf(w, 0.f);
            w = fmaf(fmaf(c1.x+ab2.x, s0.x, s0.y), gb2.x, bb2.x); af[4] = (_Float16)fmaxf(w, 0.f);
            w = fmaf(fmaf(c1.y+ab2.y, s0.x, s0.y), gb2.y, bb2.y); af[5] = (_Float16)fmaxf(w, 0.f);
            w = fmaf(fmaf(c1.z+ab2.z, s0.x, s0.y), gb2.z, bb2.z); af[6] = (_Float16)fmaxf(w, 0.f);
            w = fmaf(fmaf(c1.w+ab2.w, s0.x, s0.y), gb2.w, bb2.w); af[7] = (_Float16)fmaxf(w, 0.f);
            acc0 = __builtin_amdgcn_mfma_f32_16x16x32_f16(af, bf, acc0, 0, 0, 0);
        }
        {
            float4 c0 = *(const float4*)&r1[k], c1 = *(const float4*)&r1[k+4];
            half8 af;
            w = fmaf(fmaf(c0.x+aa.x,  s1.x, s1.y), ga.x,  ba.x);  af[0] = (_Float16)fmaxf(w, 0.f);
            w = fmaf(fmaf(c0.y+aa.y,  s1.x, s1.y), ga.y,  ba.y);  af[1] = (_Float16)fmaxf(w, 0.f);
            w = fmaf(fmaf(c0.z+aa.z,  s1.x, s1.y), ga.z,  ba.z);  af[2] = (_Float16)fmaxf(w, 0.f);
            w = fmaf(fmaf(c0.w+aa.w,  s1.x, s1.y), ga.w,  ba.w);  af[3] = (_Float16)fmaxf(w, 0.f);
            w = fmaf(fmaf(c1.x+ab2.x, s1.x, s1.y), gb2.x, bb2.x); af[4] = (_Float16)fmaxf(w, 0.f);
            w = fmaf(fmaf(c1.y+ab2.y, s1.x, s1.y), gb2.y, bb2.y); af[5] = (_Float16)fmaxf(w, 0.f);
            w = fmaf(fmaf(c1.z+ab2.z, s1.x, s1.y), gb2.z, bb2.z); af[6] = (_Float16)fmaxf(w, 0.f);
            w = fmaf(fmaf(c1.w+ab2.w, s1.x, s1.y), gb2.w, bb2.w); af[7] = (_Float16)fmaxf(w, 0.f);
            acc1 = __builtin_amdgcn_mfma_f32_16x16x32_f16(af, bf, acc1, 0, 0, 0);
        }
    }

    if (m16 < 8) {
        float basev = baseh[m16];
        #pragma unroll
        for (int r = 0; r < 4; r++) {
            int jr = wave*32 + quad*4 + r;
            float val = basev + klds[m16][jr];
            val += (jr == 0) ? -1e9f : (float)acc0[r];
            PL[m16][jr] = val;
        }
        #pragma unroll
        for (int r = 0; r < 4; r++) {
            int jr = wave*32 + 16 + quad*4 + r;
            PL[m16][jr] = basev + klds[m16][jr] + (float)acc1[r];
        }
    }
    __syncthreads();

    int j = tid & 255;
    int half = tid >> 8;

    if (tid < 256) {
        int h = tid >> 5, sgl = tid & 31;
        float mval = -INFINITY;
        #pragma unroll
        for (int r = 0; r < 8; r++) mval = fmaxf(mval, PL[h][sgl + r*32]);
        #pragma unroll
        for (int off = 16; off >= 1; off >>= 1)
            mval = fmaxf(mval, __shfl_xor(mval, off, 64));
        if (sgl == 0) mx[h] = mval;
    }
    __syncthreads();

    float p[8];
    if (half == 0) {
        #pragma unroll
        for (int h = 0; h < 8; h++) p[h] = expf(PL[h][j] - mx[h]);
    }
    __syncthreads();
    if (half == 0) {
        #pragma unroll
        for (int h = 0; h < 8; h++) PL[h][j] = p[h];
    }
    __syncthreads();

    if (tid < 256) {
        int h = tid >> 5, sgl = tid & 31;
        float sv = 0.f;
        #pragma unroll
        for (int r = 0; r < 8; r++) sv += PL[h][sgl + r*32];
        #pragma unroll
        for (int off = 16; off >= 1; off >>= 1)
            sv += __shfl_xor(sv, off, 64);
        if (sgl == 0) sm[h] = sv;
    }
    __syncthreads();

    if (half == 0) {
        float* attnOut = out + B*S1*D;
        #pragma unroll
        for (int h = 0; h < 8; h++)
            attnOut[((b*8+h)*256 + i)*256 + j] = p[h] / sm[h];
    }

    {
        int col = j;
        int h = col >> 5;
        const float* v = ws + WS_V + b*65536;
        int jb = half * 128;
        float c0 = 0.f;
        #pragma unroll 4
        for (int t = 0; t < 128; t += 4) {
            float4 pv = *(const float4*)&PL[h][jb + t];
            c0 = fmaf(pv.x, v[(jb + t    )*256 + col], c0);
            c0 = fmaf(pv.y, v[(jb + t + 1)*256 + col], c0);
            c0 = fmaf(pv.z, v[(jb + t + 2)*256 + col], c0);
            c0 = fmaf(pv.w, v[(jb + t + 3)*256 + col], c0);
        }
        cpart[tid] = c0;
    }
    __syncthreads();
    if (half == 0) {
        int h = j >> 5;
        out[(b*256 + i)*256 + j] = (cpart[tid] + cpart[tid + 256]) * (1.0f / sm[h]);
    }
}

// ---------------------------------------------------------------------------
extern "C" void kernel_launch(void* const* d_in, const int* in_sizes, int n_in,
                              void* d_out, int out_size, void* d_ws, size_t ws_size,
                              hipStream_t stream)
{
    const float* desc = (const float*)d_in[0];
    const float* nve  = (const float*)d_in[1];
    const float* qW   = (const float*)d_in[2];
    const float* qb   = (const float*)d_in[3];
    const float* kW   = (const float*)d_in[4];
    const float* kb   = (const float*)d_in[5];
    const float* vW   = (const float*)d_in[6];
    const float* vb   = (const float*)d_in[7];
    const float* eW1  = (const float*)d_in[8];
    const float* eb1  = (const float*)d_in[9];
    const float* ln_g = (const float*)d_in[10];
    const float* ln_b = (const float*)d_in[11];
    const float* eW2  = (const float*)d_in[12];
    const float* eb2  = (const float*)d_in[13];
    const float* aW   = (const float*)d_in[14];
    const float* ab   = (const float*)d_in[15];
    float* ws  = (float*)d_ws;
    float* out = (float*)d_out;

    // zero stats accumulators SA..QB (4096 floats)
    hipMemsetAsync((char*)d_ws + (size_t)WS_SA*4, 0, 4096*4, stream);

    kA<<<dim3(176, 2), 512, 0, stream>>>(desc, nve, qW, qb, kW, kb, vW, eW1,
                                         eW2, eb2, aW, ws);
    kB<<<dim3(16, 4, 4), 256, 0, stream>>>(vb, eb1, ws);
    kC<<<dim3(4, 4, 5), 256, 0, stream>>>(ws);
    kD<<<dim3(256, 4), 512, 0, stream>>>(ln_g, ln_b, ab, ws, out);
}

// Round 7
// 137.320 us; speedup vs baseline: 1.9380x; 1.3391x over previous
//
#include <hip/hip_runtime.h>
#include <math.h>

#define S 255
#define B 4

typedef _Float16 half8 __attribute__((ext_vector_type(8)));
typedef float f32x4 __attribute__((ext_vector_type(4)));

// ---- workspace layout (float offsets) ----
// frag layout for a 256x256 (row r, k) f16 matrix:
//   addr(r,k) = ((rt*8 + ks)*64 + (r&15) + 16*((k>>3)&3))*8 + (k&7),  rt=r>>4, ks=k>>5
#define WS_APJ   0          // f16[4][65536]  A' frag, row j holds A'[j-1], j=0 zeroed
#define WS_BPJ   131072     // f16[4][65536]  B' frag, j-shifted
#define WS_VTF   262144     // f16[4][65536]  V^T frag: (col, k=j)
#define WS_ATT   393216     // f16[4][8][65536] attn frag: (i, k=j)
#define WS_AP    1441792    // f32[1020][256] row-major A' (for aL)
#define WS_GJ    1703936    // f32[4][256][256]  GJ[i][j] = A'[i-1]·B'[j-1]
#define WS_MFG   1966080    // f16[4096] M in B-frag order
#define WS_CONST 1968128    // f32[8]
#define WS_QLOG  1968192    // f32[4][8][256]
#define WS_KLOG  1976384
#define WS_SA    1984576    // f32[4][256], j-indexed (entry j = stats of row j-1)
#define WS_QA    1985600
#define WS_SB    1986624
#define WS_QB    1987648    // memset region SA..QB = 4096 floats

// ===========================================================================
// K1: blocks 0..63 V->VTF | 64..127 A' | 128..191 B' | 192..207 qklog | 208 misc
// ===========================================================================
__global__ __launch_bounds__(256) void k1(
    const float* __restrict__ desc, const float* __restrict__ nve,
    const float* __restrict__ qW, const float* __restrict__ qb,
    const float* __restrict__ kW, const float* __restrict__ kb,
    const float* __restrict__ vW, const float* __restrict__ vb,
    const float* __restrict__ eW1, const float* __restrict__ eb1,
    const float* __restrict__ eW2, const float* __restrict__ eb2,
    const float* __restrict__ aW, float* __restrict__ ws)
{
    const int blk = blockIdx.x;
    const int tid = threadIdx.x;
    __shared__ _Float16 Af[4096];
    __shared__ _Float16 Bf[4096];
    const int wave = tid >> 6, lane = tid & 63;
    const int m16 = lane & 15, quad = lane >> 4;
    const int sr = tid & 63, sko = (tid >> 6) * 16;
    const half8 z8 = {(_Float16)0,(_Float16)0,(_Float16)0,(_Float16)0,
                      (_Float16)0,(_Float16)0,(_Float16)0,(_Float16)0};

    if (blk < 192) {
        const float *X, *W; int M, wst, wof, jobt, sub = blk;
        if (sub < 64)       { X=nve;  W=vW;  M=1024; wst=256; wof=0;   jobt=0; }
        else if (sub < 128) { X=desc; W=eW1; M=1020; wst=512; wof=0;   jobt=1; sub-=64; }
        else                { X=desc; W=eW1; M=1020; wst=512; wof=256; jobt=2; sub-=128; }
        int mBase = (sub>>2)*64, nBase = (sub&3)*64;
        f32x4 acc[2][2] = {};
        for (int k0 = 0; k0 < 256; k0 += 64) {
            half8 xa[2], wb[2];
            int xr = mBase + sr, wr = nBase + sr;
            #pragma unroll
            for (int hh = 0; hh < 2; hh++) {
                int kk = k0 + sko + hh*8;
                if (xr < M) {
                    float4 x0 = *(const float4*)&X[xr*256 + kk];
                    float4 x1 = *(const float4*)&X[xr*256 + kk + 4];
                    half8 hv;
                    hv[0]=(_Float16)x0.x; hv[1]=(_Float16)x0.y; hv[2]=(_Float16)x0.z; hv[3]=(_Float16)x0.w;
                    hv[4]=(_Float16)x1.x; hv[5]=(_Float16)x1.y; hv[6]=(_Float16)x1.z; hv[7]=(_Float16)x1.w;
                    xa[hh] = hv;
                } else xa[hh] = z8;
                float4 w0 = *(const float4*)&W[wr*wst + wof + kk];
                float4 w1 = *(const float4*)&W[wr*wst + wof + kk + 4];
                half8 hw;
                hw[0]=(_Float16)w0.x; hw[1]=(_Float16)w0.y; hw[2]=(_Float16)w0.z; hw[3]=(_Float16)w0.w;
                hw[4]=(_Float16)w1.x; hw[5]=(_Float16)w1.y; hw[6]=(_Float16)w1.z; hw[7]=(_Float16)w1.w;
                wb[hh] = hw;
            }
            __syncthreads();
            #pragma unroll
            for (int hh = 0; hh < 2; hh++) {
                int krel = sko + hh*8;
                int c = krel >> 5, q2 = (krel >> 3) & 3;
                int ld = (sr & 15) + 16*q2, rt = sr >> 4;
                *(half8*)&Af[((rt*2 + c)*64 + ld)*8] = xa[hh];
                *(half8*)&Bf[((rt*2 + c)*64 + ld)*8] = wb[hh];
            }
            __syncthreads();
            int rt0 = (wave >> 1)*2, ct0 = (wave & 1)*2;
            #pragma unroll
            for (int c = 0; c < 2; c++) {
                half8 A0 = *(const half8*)&Af[(((rt0    )*2 + c)*64 + lane)*8];
                half8 A1 = *(const half8*)&Af[(((rt0 + 1)*2 + c)*64 + lane)*8];
                half8 B0 = *(const half8*)&Bf[(((ct0    )*2 + c)*64 + lane)*8];
                half8 B1 = *(const half8*)&Bf[(((ct0 + 1)*2 + c)*64 + lane)*8];
                acc[0][0] = __builtin_amdgcn_mfma_f32_16x16x32_f16(A0, B0, acc[0][0], 0,0,0);
                acc[0][1] = __builtin_amdgcn_mfma_f32_16x16x32_f16(A0, B1, acc[0][1], 0,0,0);
                acc[1][0] = __builtin_amdgcn_mfma_f32_16x16x32_f16(A1, B0, acc[1][0], 0,0,0);
                acc[1][1] = __builtin_amdgcn_mfma_f32_16x16x32_f16(A1, B1, acc[1][1], 0,0,0);
            }
        }
        int rt0 = (wave >> 1)*2, ct0 = (wave & 1)*2;
        if (jobt == 0) {
            _Float16* vtf = (_Float16*)(ws + WS_VTF);
            #pragma unroll
            for (int ci = 0; ci < 2; ci++) {
                int col = nBase + (ct0 + ci)*16 + m16;
                float bv = vb[col];
                int ct = col >> 4, n = col & 15;
                #pragma unroll
                for (int ri = 0; ri < 2; ri++)
                    #pragma unroll
                    for (int r = 0; r < 4; r++) {
                        int rr = mBase + (rt0 + ri)*16 + quad*4 + r;
                        int bb = rr >> 8, j = rr & 255;
                        int js = j >> 5, qv = (j >> 3) & 3, ev = j & 7;
                        float o = acc[ri][ci][r] + bv;
                        vtf[bb*65536 + (((ct*8 + js)*64 + n + 16*qv) << 3) + ev] = (_Float16)o;
                    }
            }
        } else {
            _Float16* OJ = (_Float16*)(ws + ((jobt == 1) ? WS_APJ : WS_BPJ));
            float* Sp = ws + ((jobt == 1) ? WS_SA : WS_SB);
            float* Qp = ws + ((jobt == 1) ? WS_QA : WS_QB);
            float svr[2][4] = {}, qvr[2][4] = {};
            #pragma unroll
            for (int ci = 0; ci < 2; ci++) {
                int col = nBase + (ct0 + ci)*16 + m16;
                float bv = (jobt == 1) ? eb1[col] : 0.f;
                int ks = col >> 5, q = (col >> 3) & 3, e = col & 7;
                #pragma unroll
                for (int ri = 0; ri < 2; ri++)
                    #pragma unroll
                    for (int r = 0; r < 4; r++) {
                        int rr = mBase + (rt0 + ri)*16 + quad*4 + r;
                        if (rr < 1020) {
                            float o = acc[ri][ci][r] + bv;
                            int bb = rr / 255;
                            int j = rr - bb*255 + 1;
                            int jt = j >> 4, mm = j & 15;
                            OJ[bb*65536 + (((jt*8 + ks)*64 + mm + 16*q) << 3) + e] = (_Float16)o;
                            if (jobt == 1) ws[WS_AP + rr*256 + col] = o;
                            svr[ri][r] += o;
                            qvr[ri][r] = fmaf(o, o, qvr[ri][r]);
                        }
                    }
            }
            #pragma unroll
            for (int ri = 0; ri < 2; ri++)
                #pragma unroll
                for (int r = 0; r < 4; r++) {
                    float s = svr[ri][r], q = qvr[ri][r];
                    #pragma unroll
                    for (int d = 1; d < 16; d <<= 1) {
                        s += __shfl_xor(s, d, 64);
                        q += __shfl_xor(q, d, 64);
                    }
                    int rr = mBase + (rt0 + ri)*16 + quad*4 + r;
                    if (m16 == 0 && rr < 1020) {
                        int bb = rr / 255;
                        int j = rr - bb*255 + 1;
                        atomicAdd(&Sp[bb*256 + j], s);
                        atomicAdd(&Qp[bb*256 + j], q);
                    }
                }
        }
    } else if (blk < 208) {
        // qklog = nve @ fold  (fold in Bf)
        {
            int d = tid;
            float f[16] = {0,0,0,0,0,0,0,0,0,0,0,0,0,0,0,0};
            for (int hd = 0; hd < 32; hd++) {
                float wq = aW[hd], wk = aW[32+hd];
                #pragma unroll
                for (int h = 0; h < 8; h++) {
                    f[h]   = fmaf(wq, qW[(h*32+hd)*256 + d], f[h]);
                    f[8+h] = fmaf(wk, kW[(h*32+hd)*256 + d], f[8+h]);
                }
            }
            int ksd = d >> 5, q2 = (d >> 3) & 3, jj = d & 7;
            #pragma unroll
            for (int n = 0; n < 16; n++)
                Bf[((ksd*64 + n + 16*q2))*8 + jj] = (_Float16)f[n];
        }
        __syncthreads();
        int mBase = (blk - 192)*64;
        f32x4 acc = {0.f,0.f,0.f,0.f};
        for (int k0 = 0; k0 < 256; k0 += 64) {
            half8 xa[2];
            #pragma unroll
            for (int hh = 0; hh < 2; hh++) {
                int kk = k0 + sko + hh*8;
                float4 x0 = *(const float4*)&nve[(mBase + sr)*256 + kk];
                float4 x1 = *(const float4*)&nve[(mBase + sr)*256 + kk + 4];
                half8 hv;
                hv[0]=(_Float16)x0.x; hv[1]=(_Float16)x0.y; hv[2]=(_Float16)x0.z; hv[3]=(_Float16)x0.w;
                hv[4]=(_Float16)x1.x; hv[5]=(_Float16)x1.y; hv[6]=(_Float16)x1.z; hv[7]=(_Float16)x1.w;
                xa[hh] = hv;
            }
            __syncthreads();
            #pragma unroll
            for (int hh = 0; hh < 2; hh++) {
                int krel = sko + hh*8;
                int c = krel >> 5, q2 = (krel >> 3) & 3;
                int ld = (sr & 15) + 16*q2, rt = sr >> 4;
                *(half8*)&Af[((rt*2 + c)*64 + ld)*8] = xa[hh];
            }
            __syncthreads();
            #pragma unroll
            for (int c = 0; c < 2; c++) {
                half8 A  = *(const half8*)&Af[((wave*2 + c)*64 + lane)*8];
                half8 Bv = *(const half8*)&Bf[(((k0 >> 5) + c)*64 + lane)*8];
                acc = __builtin_amdgcn_mfma_f32_16x16x32_f16(A, Bv, acc, 0,0,0);
            }
        }
        #pragma unroll
        for (int r = 0; r < 4; r++) {
            int rr = mBase + wave*16 + quad*4 + r;
            int bb = rr >> 8, tt2 = rr & 255;
            if (m16 < 8) ws[WS_QLOG + (bb*8 + m16)*256 + tt2] = acc[r];
            else         ws[WS_KLOG + (bb*8 + m16 - 8)*256 + tt2] = acc[r];
        }
    } else {
        // misc: MFG + CONST + zero j=0 frag slots
        _Float16* mfg = (_Float16*)(ws + WS_MFG);
        int k = tid;
        float a8[8] = {0,0,0,0,0,0,0,0};
        for (int hd = 0; hd < 32; hd++) {
            float we = aW[64+hd];
            #pragma unroll
            for (int h = 0; h < 8; h++)
                a8[h] = fmaf(we, eW2[(h*32+hd)*256 + k], a8[h]);
        }
        int ksd = k >> 5, q2 = (k >> 3) & 3, jj = k & 7;
        #pragma unroll
        for (int h = 0; h < 8; h++)
            mfg[((ksd*64 + h + 16*q2))*8 + jj] = (_Float16)a8[h];
        #pragma unroll
        for (int n = 8; n < 16; n++)
            mfg[((ksd*64 + n + 16*q2))*8 + jj] = (_Float16)0.f;
        // zero j=0 slots of APJ/BPJ (jt=0, m=0): ks=tid>>5, q=(tid>>3)&3, e=tid&7
        {
            _Float16* apj = (_Float16*)(ws + WS_APJ);
            _Float16* bpj = (_Float16*)(ws + WS_BPJ);
            int ks0 = tid >> 5, qz = (tid >> 3) & 3, ez = tid & 7;
            int ad = ((ks0*64 + 16*qz) << 3) + ez;
            #pragma unroll
            for (int bb = 0; bb < 4; bb++) {
                apj[bb*65536 + ad] = (_Float16)0.f;
                bpj[bb*65536 + ad] = (_Float16)0.f;
            }
        }
        if (tid == 0) {
            #pragma unroll
            for (int h = 0; h < 8; h++) {
                float c = 0.f;
                for (int hd = 0; hd < 32; hd++) {
                    c = fmaf(aW[64+hd], eb2[h*32+hd], c);
                    c = fmaf(aW[hd],    qb [h*32+hd], c);
                    c = fmaf(aW[32+hd], kb [h*32+hd], c);
                }
                ws[WS_CONST + h] = c;
            }
        }
    }
}

// ===========================================================================
// K2: GJ = APJ @ BPJ^T, direct frag loads, no LDS.  grid (16,4) x 256
// ===========================================================================
__global__ __launch_bounds__(256) void k2(float* __restrict__ ws)
{
    int b = blockIdx.y;
    int x = blockIdx.x;
    int tid = threadIdx.x;
    int wave = tid >> 6, lane = tid & 63;
    int m16 = lane & 15, quad = lane >> 4;
    int rt = (x >> 2)*4 + (wave >> 1)*2;
    int ct = (x & 3)*4 + (wave & 1)*2;
    const _Float16* apj = (const _Float16*)(ws + WS_APJ) + b*65536;
    const _Float16* bpj = (const _Float16*)(ws + WS_BPJ) + b*65536;
    f32x4 acc[2][2] = {};
    #pragma unroll
    for (int ks = 0; ks < 8; ks++) {
        half8 A0 = *(const half8*)&apj[(((rt    )*8 + ks)*64 + lane) << 3];
        half8 A1 = *(const half8*)&apj[(((rt + 1)*8 + ks)*64 + lane) << 3];
        half8 B0 = *(const half8*)&bpj[(((ct    )*8 + ks)*64 + lane) << 3];
        half8 B1 = *(const half8*)&bpj[(((ct + 1)*8 + ks)*64 + lane) << 3];
        acc[0][0] = __builtin_amdgcn_mfma_f32_16x16x32_f16(A0, B0, acc[0][0], 0,0,0);
        acc[0][1] = __builtin_amdgcn_mfma_f32_16x16x32_f16(A0, B1, acc[0][1], 0,0,0);
        acc[1][0] = __builtin_amdgcn_mfma_f32_16x16x32_f16(A1, B0, acc[1][0], 0,0,0);
        acc[1][1] = __builtin_amdgcn_mfma_f32_16x16x32_f16(A1, B1, acc[1][1], 0,0,0);
    }
    float* gj = ws + WS_GJ + (size_t)b*65536;
    #pragma unroll
    for (int ci = 0; ci < 2; ci++) {
        int col = (ct + ci)*16 + m16;
        #pragma unroll
        for (int ri = 0; ri < 2; ri++)
            #pragma unroll
            for (int r = 0; r < 4; r++)
                gj[((rt + ri)*16 + quad*4 + r)*256 + col] = acc[ri][ci][r];
    }
}

// ===========================================================================
// K3: logits + softmax + attn (f32 out + f16 frag).  grid (256,4) x 256
// ===========================================================================
__global__ __launch_bounds__(256, 4) void k3(
    const float* __restrict__ ln_g, const float* __restrict__ ln_b,
    const float* __restrict__ ab, const float* __restrict__ ws,
    float* __restrict__ out)
{
    int b = blockIdx.y, i = blockIdx.x;
    int tid = threadIdx.x;
    __shared__ float klds[2048];
    __shared__ float PL[2048];
    __shared__ float gL[256], bL[256], aL[256];
    __shared__ float2 st[256];
    __shared__ float baseh[8], mxs[8], sms[8];

    #pragma unroll
    for (int t = 0; t < 8; t++)
        klds[tid + t*256] = ws[WS_KLOG + b*2048 + tid + t*256];
    gL[tid] = ln_g[tid];
    bL[tid] = ln_b[tid];
    aL[tid] = (i >= 1) ? ws[WS_AP + ((size_t)(b*S + i - 1))*256 + tid] : 0.f;
    if (tid < 8)
        baseh[tid] = ws[WS_QLOG + (b*8+tid)*256 + i] + ab[0] + ws[WS_CONST + tid];
    {
        int j = tid;
        float2 v; v.x = 0.f; v.y = 0.f;
        if (j >= 1) {
            float sa, qa, sb, qb2, g;
            if (i >= 1) {
                sa = ws[WS_SA + b*256 + i]; qa = ws[WS_QA + b*256 + i];
                sb = ws[WS_SB + b*256 + j]; qb2 = ws[WS_QB + b*256 + j];
                g  = ws[WS_GJ + (size_t)b*65536 + i*256 + j];
            } else {
                sa = ws[WS_SA + b*256 + j]; qa = ws[WS_QA + b*256 + j];
                sb = ws[WS_SB + b*256 + j]; qb2 = ws[WS_QB + b*256 + j];
                g  = ws[WS_GJ + (size_t)b*65536 + j*256 + j];
            }
            float mu  = (sa + sb) * (1.0f/256.0f);
            float var = (qa + qb2 + 2.f*g) * (1.0f/256.0f) - mu*mu;
            float inv = rsqrtf(var + 1e-5f);
            v.x = inv; v.y = -mu*inv;
        }
        st[j] = v;
    }
    __syncthreads();

    int wave = tid >> 6, lane = tid & 63;
    int m16 = lane & 15, quad = lane >> 4;
    const _Float16* mfg = (const _Float16*)(ws + WS_MFG);
    const _Float16* bpj = (const _Float16*)(ws + WS_BPJ) + b*65536;
    const _Float16* apj = (const _Float16*)(ws + WS_APJ) + b*65536;
    f32x4 acc[4] = {};
    float2 sv[4];
    #pragma unroll
    for (int tt = 0; tt < 4; tt++)
        sv[tt] = st[(wave*4 + tt)*16 + m16];

    if (i >= 1) {
        #pragma unroll
        for (int ks = 0; ks < 8; ks++) {
            int k = ks*32 + quad*8;
            float4 a0 = *(const float4*)&aL[k], a1 = *(const float4*)&aL[k+4];
            float4 g0 = *(const float4*)&gL[k], g1 = *(const float4*)&gL[k+4];
            float4 b0 = *(const float4*)&bL[k], b1 = *(const float4*)&bL[k+4];
            half8 bf = *(const half8*)&mfg[(ks*64 + lane) << 3];
            float aa[8] = {a0.x,a0.y,a0.z,a0.w,a1.x,a1.y,a1.z,a1.w};
            float ga[8] = {g0.x,g0.y,g0.z,g0.w,g1.x,g1.y,g1.z,g1.w};
            float be[8] = {b0.x,b0.y,b0.z,b0.w,b1.x,b1.y,b1.z,b1.w};
            #pragma unroll
            for (int tt = 0; tt < 4; tt++) {
                half8 bp = *(const half8*)&bpj[(((wave*4 + tt)*8 + ks)*64 + lane) << 3];
                half8 af;
                #pragma unroll
                for (int e = 0; e < 8; e++) {
                    float c = (float)bp[e] + aa[e];
                    float w = fmaf(fmaf(c, sv[tt].x, sv[tt].y), ga[e], be[e]);
                    af[e] = (_Float16)fmaxf(w, 0.f);
                }
                acc[tt] = __builtin_amdgcn_mfma_f32_16x16x32_f16(af, bf, acc[tt], 0,0,0);
            }
        }
    } else {
        #pragma unroll
        for (int ks = 0; ks < 8; ks++) {
            int k = ks*32 + quad*8;
            float4 g0 = *(const float4*)&gL[k], g1 = *(const float4*)&gL[k+4];
            float4 b0 = *(const float4*)&bL[k], b1 = *(const float4*)&bL[k+4];
            half8 bf = *(const half8*)&mfg[(ks*64 + lane) << 3];
            float ga[8] = {g0.x,g0.y,g0.z,g0.w,g1.x,g1.y,g1.z,g1.w};
            float be[8] = {b0.x,b0.y,b0.z,b0.w,b1.x,b1.y,b1.z,b1.w};
            #pragma unroll
            for (int tt = 0; tt < 4; tt++) {
                int idx = ((((wave*4 + tt)*8 + ks)*64 + lane) << 3);
                half8 bp = *(const half8*)&bpj[idx];
                half8 ap = *(const half8*)&apj[idx];
                half8 af;
                #pragma unroll
                for (int e = 0; e < 8; e++) {
                    float c = (float)ap[e] + (float)bp[e];
                    float w = fmaf(fmaf(c, sv[tt].x, sv[tt].y), ga[e], be[e]);
                    af[e] = (_Float16)fmaxf(w, 0.f);
                }
                acc[tt] = __builtin_amdgcn_mfma_f32_16x16x32_f16(af, bf, acc[tt], 0,0,0);
            }
        }
    }

    if (m16 < 8) {
        float basev = baseh[m16];
        #pragma unroll
        for (int tt = 0; tt < 4; tt++)
            #pragma unroll
            for (int r = 0; r < 4; r++) {
                int jr = (wave*4 + tt)*16 + quad*4 + r;
                float val = basev + klds[m16*256 + jr];
                val += (jr == 0) ? -1e9f : acc[tt][r];
                PL[m16*256 + jr] = val;
            }
    }
    __syncthreads();

    {
        int h = tid >> 5, sg = tid & 31;
        float mv = -INFINITY;
        #pragma unroll
        for (int r = 0; r < 8; r++) mv = fmaxf(mv, PL[h*256 + sg + r*32]);
        #pragma unroll
        for (int off = 16; off >= 1; off >>= 1)
            mv = fmaxf(mv, __shfl_xor(mv, off, 64));
        if (sg == 0) mxs[h] = mv;
    }
    __syncthreads();
    float p[8];
    #pragma unroll
    for (int h = 0; h < 8; h++) p[h] = expf(PL[h*256 + tid] - mxs[h]);
    __syncthreads();
    #pragma unroll
    for (int h = 0; h < 8; h++) PL[h*256 + tid] = p[h];
    __syncthreads();
    {
        int h = tid >> 5, sg = tid & 31;
        float sv2 = 0.f;
        #pragma unroll
        for (int r = 0; r < 8; r++) sv2 += PL[h*256 + sg + r*32];
        #pragma unroll
        for (int off = 16; off >= 1; off >>= 1)
            sv2 += __shfl_xor(sv2, off, 64);
        if (sg == 0) sms[h] = sv2;
    }
    __syncthreads();

    float* attnOut = out + 262144;
    _Float16* att = (_Float16*)(ws + WS_ATT);
    int it = i >> 4, mi = i & 15;
    int js = tid >> 5, qj = (tid >> 3) & 3, ej = tid & 7;
    int fad = (((it*8 + js)*64 + mi + 16*qj) << 3) + ej;
    #pragma unroll
    for (int h = 0; h < 8; h++) {
        float a = p[h] / sms[h];
        attnOut[((b*8+h)*256 + i)*256 + tid] = a;
        att[(b*8+h)*65536 + fad] = (_Float16)a;
    }
}

// ===========================================================================
// K4: ctx = attn @ V, direct frag loads.  grid 128 x 256
// ===========================================================================
__global__ __launch_bounds__(256) void k4(const float* __restrict__ ws,
                                          float* __restrict__ out)
{
    int blk = blockIdx.x;
    int b = blk >> 5, h = (blk >> 2) & 7, mq = blk & 3;
    int tid = threadIdx.x;
    int wave = tid >> 6, lane = tid & 63;
    int m16 = lane & 15, quad = lane >> 4;
    int it = mq*4 + wave;
    const _Float16* att = (const _Float16*)(ws + WS_ATT) + (size_t)(b*8 + h)*65536;
    const _Float16* vtf = (const _Float16*)(ws + WS_VTF) + (size_t)b*65536;
    int ct0 = h*2;
    f32x4 acc[2] = {};
    #pragma unroll
    for (int js = 0; js < 8; js++) {
        half8 A  = *(const half8*)&att[((it*8 + js)*64 + lane) << 3];
        half8 B0 = *(const half8*)&vtf[(((ct0    )*8 + js)*64 + lane) << 3];
        half8 B1 = *(const half8*)&vtf[(((ct0 + 1)*8 + js)*64 + lane) << 3];
        acc[0] = __builtin_amdgcn_mfma_f32_16x16x32_f16(A, B0, acc[0], 0,0,0);
        acc[1] = __builtin_amdgcn_mfma_f32_16x16x32_f16(A, B1, acc[1], 0,0,0);
    }
    #pragma unroll
    for (int nt = 0; nt < 2; nt++) {
        int col = h*32 + nt*16 + m16;
        #pragma unroll
        for (int r = 0; r < 4; r++) {
            int row = it*16 + quad*4 + r;
            out[(b*256 + row)*256 + col] = acc[nt][r];
        }
    }
}

// ---------------------------------------------------------------------------
extern "C" void kernel_launch(void* const* d_in, const int* in_sizes, int n_in,
                              void* d_out, int out_size, void* d_ws, size_t ws_size,
                              hipStream_t stream)
{
    const float* desc = (const float*)d_in[0];
    const float* nve  = (const float*)d_in[1];
    const float* qW   = (const float*)d_in[2];
    const float* qb   = (const float*)d_in[3];
    const float* kW   = (const float*)d_in[4];
    const float* kb   = (const float*)d_in[5];
    const float* vW   = (const float*)d_in[6];
    const float* vb   = (const float*)d_in[7];
    const float* eW1  = (const float*)d_in[8];
    const float* eb1  = (const float*)d_in[9];
    const float* ln_g = (const float*)d_in[10];
    const float* ln_b = (const float*)d_in[11];
    const float* eW2  = (const float*)d_in[12];
    const float* eb2  = (const float*)d_in[13];
    const float* aW   = (const float*)d_in[14];
    const float* ab   = (const float*)d_in[15];
    float* ws  = (float*)d_ws;
    float* out = (float*)d_out;

    hipMemsetAsync((char*)d_ws + (size_t)WS_SA*4, 0, 4096*4, stream);
    k1<<<dim3(209), 256, 0, stream>>>(desc, nve, qW, qb, kW, kb, vW, vb,
                                      eW1, eb1, eW2, eb2, aW, ws);
    k2<<<dim3(16, 4), 256, 0, stream>>>(ws);
    k3<<<dim3(256, 4), 256, 0, stream>>>(ln_g, ln_b, ab, ws, out);
    k4<<<dim3(128), 256, 0, stream>>>(ws, out);
}

// Round 8
// 137.118 us; speedup vs baseline: 1.9409x; 1.0015x over previous
//
#include <hip/hip_runtime.h>
#include <math.h>

#define S 255
#define B 4

typedef _Float16 half8 __attribute__((ext_vector_type(8)));
typedef float f32x4 __attribute__((ext_vector_type(4)));

// ---- workspace layout (float offsets) ----
// frag layout for a 256x256 (row r, k) f16 matrix:
//   addr(r,k) = ((rt*8 + ks)*64 + (r&15) + 16*((k>>3)&3))*8 + (k&7)
#define WS_APJ   0          // f16[4][65536]  A' frag, row j = A'[j-1], j=0 zeroed
#define WS_BPJ   131072     // f16[4][65536]  B' frag, j-shifted
#define WS_VTF   262144     // f16[4][65536]  V^T frag: (col d, k=j)
#define WS_AP    393216     // f32[1020][256] row-major A'
#define WS_MFG   654336     // f16[4096] M in B-frag order
#define WS_CONST 656384     // f32[8]
#define WS_QLOG  656392     // f32[4][8][256]
#define WS_KLOG  664584     // f32[4][8][256]  (ends 672776)

__device__ __forceinline__ half8 cvt8(float4 a, float4 b) {
    half8 h;
    h[0]=(_Float16)a.x; h[1]=(_Float16)a.y; h[2]=(_Float16)a.z; h[3]=(_Float16)a.w;
    h[4]=(_Float16)b.x; h[5]=(_Float16)b.y; h[6]=(_Float16)b.z; h[7]=(_Float16)b.w;
    return h;
}

// ===========================================================================
// K1: 0..63 V->VTF | 64..127 A' | 128..191 B' | 192..207 qklog | 208 misc
// ===========================================================================
__global__ __launch_bounds__(256) void k1(
    const float* __restrict__ desc, const float* __restrict__ nve,
    const float* __restrict__ qW, const float* __restrict__ qb,
    const float* __restrict__ kW, const float* __restrict__ kb,
    const float* __restrict__ vW, const float* __restrict__ vb,
    const float* __restrict__ eW1, const float* __restrict__ eb1,
    const float* __restrict__ eW2, const float* __restrict__ eb2,
    const float* __restrict__ aW, float* __restrict__ ws)
{
    const int blk = blockIdx.x;
    const int tid = threadIdx.x;
    __shared__ _Float16 Af[4096];
    __shared__ _Float16 Bf[4096];
    const int wave = tid >> 6, lane = tid & 63;
    const int m16 = lane & 15, quad = lane >> 4;
    const int sr = tid & 63, sko = (tid >> 6) * 16;
    const half8 z8 = {(_Float16)0,(_Float16)0,(_Float16)0,(_Float16)0,
                      (_Float16)0,(_Float16)0,(_Float16)0,(_Float16)0};

    if (blk < 192) {
        const float *X, *W; int M, wst, wof, jobt, sub = blk;
        if (sub < 64)       { X=nve;  W=vW;  M=1024; wst=256; wof=0;   jobt=0; }
        else if (sub < 128) { X=desc; W=eW1; M=1020; wst=512; wof=0;   jobt=1; sub-=64; }
        else                { X=desc; W=eW1; M=1020; wst=512; wof=256; jobt=2; sub-=128; }
        int mBase = (sub>>2)*64, nBase = (sub&3)*64;
        f32x4 acc[2][2] = {};
        for (int k0 = 0; k0 < 256; k0 += 64) {
            half8 xa[2], wb[2];
            int xr = mBase + sr, wr = nBase + sr;
            #pragma unroll
            for (int hh = 0; hh < 2; hh++) {
                int kk = k0 + sko + hh*8;
                if (xr < M) xa[hh] = cvt8(*(const float4*)&X[xr*256 + kk],
                                          *(const float4*)&X[xr*256 + kk + 4]);
                else xa[hh] = z8;
                wb[hh] = cvt8(*(const float4*)&W[wr*wst + wof + kk],
                              *(const float4*)&W[wr*wst + wof + kk + 4]);
            }
            __syncthreads();
            #pragma unroll
            for (int hh = 0; hh < 2; hh++) {
                int krel = sko + hh*8;
                int c = krel >> 5, q2 = (krel >> 3) & 3;
                int ld = (sr & 15) + 16*q2, rt = sr >> 4;
                *(half8*)&Af[((rt*2 + c)*64 + ld)*8] = xa[hh];
                *(half8*)&Bf[((rt*2 + c)*64 + ld)*8] = wb[hh];
            }
            __syncthreads();
            int rt0 = (wave >> 1)*2, ct0 = (wave & 1)*2;
            #pragma unroll
            for (int c = 0; c < 2; c++) {
                half8 A0 = *(const half8*)&Af[(((rt0    )*2 + c)*64 + lane)*8];
                half8 A1 = *(const half8*)&Af[(((rt0 + 1)*2 + c)*64 + lane)*8];
                half8 B0 = *(const half8*)&Bf[(((ct0    )*2 + c)*64 + lane)*8];
                half8 B1 = *(const half8*)&Bf[(((ct0 + 1)*2 + c)*64 + lane)*8];
                acc[0][0] = __builtin_amdgcn_mfma_f32_16x16x32_f16(A0, B0, acc[0][0], 0,0,0);
                acc[0][1] = __builtin_amdgcn_mfma_f32_16x16x32_f16(A0, B1, acc[0][1], 0,0,0);
                acc[1][0] = __builtin_amdgcn_mfma_f32_16x16x32_f16(A1, B0, acc[1][0], 0,0,0);
                acc[1][1] = __builtin_amdgcn_mfma_f32_16x16x32_f16(A1, B1, acc[1][1], 0,0,0);
            }
        }
        int rt0 = (wave >> 1)*2, ct0 = (wave & 1)*2;
        if (jobt == 0) {
            _Float16* vtf = (_Float16*)(ws + WS_VTF);
            #pragma unroll
            for (int ci = 0; ci < 2; ci++) {
                int col = nBase + (ct0 + ci)*16 + m16;
                float bv = vb[col];
                int ct = col >> 4, n = col & 15;
                #pragma unroll
                for (int ri = 0; ri < 2; ri++)
                    #pragma unroll
                    for (int r = 0; r < 4; r++) {
                        int rr = mBase + (rt0 + ri)*16 + quad*4 + r;
                        int bb = rr >> 8, j = rr & 255;
                        int js = j >> 5, qv = (j >> 3) & 3, ev = j & 7;
                        float o = acc[ri][ci][r] + bv;
                        vtf[bb*65536 + (((ct*8 + js)*64 + n + 16*qv) << 3) + ev] = (_Float16)o;
                    }
            }
        } else {
            _Float16* OJ = (_Float16*)(ws + ((jobt == 1) ? WS_APJ : WS_BPJ));
            #pragma unroll
            for (int ci = 0; ci < 2; ci++) {
                int col = nBase + (ct0 + ci)*16 + m16;
                float bv = (jobt == 1) ? eb1[col] : 0.f;
                int ks = col >> 5, q = (col >> 3) & 3, e = col & 7;
                #pragma unroll
                for (int ri = 0; ri < 2; ri++)
                    #pragma unroll
                    for (int r = 0; r < 4; r++) {
                        int rr = mBase + (rt0 + ri)*16 + quad*4 + r;
                        if (rr < 1020) {
                            float o = acc[ri][ci][r] + bv;
                            int bb = rr / 255;
                            int j = rr - bb*255 + 1;
                            int jt = j >> 4, mm = j & 15;
                            OJ[bb*65536 + (((jt*8 + ks)*64 + mm + 16*q) << 3) + e] = (_Float16)o;
                            if (jobt == 1) ws[WS_AP + rr*256 + col] = o;
                        }
                    }
            }
        }
    } else if (blk < 208) {
        // qklog = nve @ fold (fold in Bf)
        {
            int d = tid;
            float f[16] = {0,0,0,0,0,0,0,0,0,0,0,0,0,0,0,0};
            for (int hd = 0; hd < 32; hd++) {
                float wq = aW[hd], wk = aW[32+hd];
                #pragma unroll
                for (int h = 0; h < 8; h++) {
                    f[h]   = fmaf(wq, qW[(h*32+hd)*256 + d], f[h]);
                    f[8+h] = fmaf(wk, kW[(h*32+hd)*256 + d], f[8+h]);
                }
            }
            int ksd = d >> 5, q2 = (d >> 3) & 3, jj = d & 7;
            #pragma unroll
            for (int n = 0; n < 16; n++)
                Bf[((ksd*64 + n + 16*q2))*8 + jj] = (_Float16)f[n];
        }
        __syncthreads();
        int mBase = (blk - 192)*64;
        f32x4 acc = {0.f,0.f,0.f,0.f};
        for (int k0 = 0; k0 < 256; k0 += 64) {
            half8 xa[2];
            #pragma unroll
            for (int hh = 0; hh < 2; hh++) {
                int kk = k0 + sko + hh*8;
                xa[hh] = cvt8(*(const float4*)&nve[(mBase + sr)*256 + kk],
                              *(const float4*)&nve[(mBase + sr)*256 + kk + 4]);
            }
            __syncthreads();
            #pragma unroll
            for (int hh = 0; hh < 2; hh++) {
                int krel = sko + hh*8;
                int c = krel >> 5, q2 = (krel >> 3) & 3;
                int ld = (sr & 15) + 16*q2, rt = sr >> 4;
                *(half8*)&Af[((rt*2 + c)*64 + ld)*8] = xa[hh];
            }
            __syncthreads();
            #pragma unroll
            for (int c = 0; c < 2; c++) {
                half8 A  = *(const half8*)&Af[((wave*2 + c)*64 + lane)*8];
                half8 Bv = *(const half8*)&Bf[(((k0 >> 5) + c)*64 + lane)*8];
                acc = __builtin_amdgcn_mfma_f32_16x16x32_f16(A, Bv, acc, 0,0,0);
            }
        }
        #pragma unroll
        for (int r = 0; r < 4; r++) {
            int rr = mBase + wave*16 + quad*4 + r;
            int bb = rr >> 8, tt2 = rr & 255;
            if (m16 < 8) ws[WS_QLOG + (bb*8 + m16)*256 + tt2] = acc[r];
            else         ws[WS_KLOG + (bb*8 + m16 - 8)*256 + tt2] = acc[r];
        }
    } else {
        // misc: MFG + CONST + zero j=0 frag rows
        _Float16* mfg = (_Float16*)(ws + WS_MFG);
        int k = tid;
        float a8[8] = {0,0,0,0,0,0,0,0};
        for (int hd = 0; hd < 32; hd++) {
            float we = aW[64+hd];
            #pragma unroll
            for (int h = 0; h < 8; h++)
                a8[h] = fmaf(we, eW2[(h*32+hd)*256 + k], a8[h]);
        }
        int ksd = k >> 5, q2 = (k >> 3) & 3, jj = k & 7;
        #pragma unroll
        for (int h = 0; h < 8; h++)
            mfg[((ksd*64 + h + 16*q2))*8 + jj] = (_Float16)a8[h];
        #pragma unroll
        for (int n = 8; n < 16; n++)
            mfg[((ksd*64 + n + 16*q2))*8 + jj] = (_Float16)0.f;
        {
            _Float16* apj = (_Float16*)(ws + WS_APJ);
            _Float16* bpj = (_Float16*)(ws + WS_BPJ);
            int ks0 = tid >> 5, qz = (tid >> 3) & 3, ez = tid & 7;
            int ad = ((ks0*64 + 16*qz) << 3) + ez;
            #pragma unroll
            for (int bb = 0; bb < 4; bb++) {
                apj[bb*65536 + ad] = (_Float16)0.f;
                bpj[bb*65536 + ad] = (_Float16)0.f;
            }
        }
        if (tid == 0) {
            #pragma unroll
            for (int h = 0; h < 8; h++) {
                float c = 0.f;
                for (int hd = 0; hd < 32; hd++) {
                    c = fmaf(aW[64+hd], eb2[h*32+hd], c);
                    c = fmaf(aW[hd],    qb [h*32+hd], c);
                    c = fmaf(aW[32+hd], kb [h*32+hd], c);
                }
                ws[WS_CONST + h] = c;
            }
        }
    }
}

// ===========================================================================
// K3: stats (MFMA) + logits (MFMA) + softmax + attn + ctx (MFMA).
// grid (256,4) x 256
// ===========================================================================
#define PLS 272

__global__ __launch_bounds__(256, 4) void k3(
    const float* __restrict__ ln_g, const float* __restrict__ ln_b,
    const float* __restrict__ ab, const float* __restrict__ ws,
    float* __restrict__ out)
{
    int b = blockIdx.y, i = blockIdx.x;
    int tid = threadIdx.x;
    __shared__ float klds[2048];
    __shared__ float PL[8*PLS];
    __shared__ float gL[256], bL[256], aL[256];
    __shared__ float2 st[256];
    __shared__ float stG[256], stSB[256], stQB[256], stSA[256], stQA[256];
    __shared__ float baseh[8], mxs[8], sms[8], saqa[8];

    int wave = tid >> 6, lane = tid & 63;
    int m16 = lane & 15, quad = lane >> 4;
    const half8 z8 = {(_Float16)0,(_Float16)0,(_Float16)0,(_Float16)0,
                      (_Float16)0,(_Float16)0,(_Float16)0,(_Float16)0};
    half8 ones8;
    #pragma unroll
    for (int e = 0; e < 8; e++) ones8[e] = (_Float16)1.0f;

    #pragma unroll
    for (int t = 0; t < 8; t++)
        klds[tid + t*256] = ws[WS_KLOG + b*2048 + tid + t*256];
    gL[tid] = ln_g[tid];
    bL[tid] = ln_b[tid];
    float av = (i >= 1) ? ws[WS_AP + ((size_t)(b*S + i - 1))*256 + tid] : 0.f;
    aL[tid] = av;
    {   // block-reduce sa,qa of aL
        float s1 = av, s2 = av*av;
        #pragma unroll
        for (int off = 32; off >= 1; off >>= 1) {
            s1 += __shfl_xor(s1, off, 64);
            s2 += __shfl_xor(s2, off, 64);
        }
        if (lane == 0) { saqa[wave] = s1; saqa[4+wave] = s2; }
    }
    if (tid < 8)
        baseh[tid] = ws[WS_QLOG + (b*8+tid)*256 + i] + ab[0] + ws[WS_CONST + tid];
    __syncthreads();

    const _Float16* mfg = (const _Float16*)(ws + WS_MFG);
    const _Float16* bpj = (const _Float16*)(ws + WS_BPJ) + b*65536;
    const _Float16* apj = (const _Float16*)(ws + WS_APJ) + b*65536;
    const _Float16* vtf = (const _Float16*)(ws + WS_VTF) + b*65536;

    // ---- phase A: per-j stats via MFMA ----
    if (i >= 1) {
        #pragma unroll
        for (int tl4 = 0; tl4 < 4; tl4++) {
            int tl = wave*4 + tl4;
            f32x4 accGS = {}, accQB = {};
            #pragma unroll
            for (int ks = 0; ks < 8; ks++) {
                half8 bb = *(const half8*)&bpj[((tl*8+ks)*64 + lane) << 3];
                half8 ags;
                if (m16 == 0)
                    ags = cvt8(*(const float4*)&aL[ks*32 + quad*8],
                               *(const float4*)&aL[ks*32 + quad*8 + 4]);
                else if (m16 == 1) ags = ones8;
                else ags = z8;
                accGS = __builtin_amdgcn_mfma_f32_16x16x32_f16(ags, bb, accGS, 0,0,0);
                accQB = __builtin_amdgcn_mfma_f32_16x16x32_f16(bb,  bb, accQB, 0,0,0);
            }
            int j = tl*16 + m16;
            if (quad == 0) { stG[j] = accGS[0]; stSB[j] = accGS[1]; }
            if (quad == (m16 >> 2)) stQB[j] = accQB[m16 & 3];
        }
    } else {
        #pragma unroll
        for (int tl4 = 0; tl4 < 4; tl4++) {
            int tl = wave*4 + tl4;
            f32x4 accSB = {}, accSA = {}, accG = {}, accQA = {}, accQB = {};
            #pragma unroll
            for (int ks = 0; ks < 8; ks++) {
                int idx = ((tl*8+ks)*64 + lane) << 3;
                half8 bb = *(const half8*)&bpj[idx];
                half8 aa = *(const half8*)&apj[idx];
                half8 a1 = (m16 == 0) ? ones8 : z8;
                accSB = __builtin_amdgcn_mfma_f32_16x16x32_f16(a1, bb, accSB, 0,0,0);
                accSA = __builtin_amdgcn_mfma_f32_16x16x32_f16(a1, aa, accSA, 0,0,0);
                accG  = __builtin_amdgcn_mfma_f32_16x16x32_f16(aa, bb, accG,  0,0,0);
                accQA = __builtin_amdgcn_mfma_f32_16x16x32_f16(aa, aa, accQA, 0,0,0);
                accQB = __builtin_amdgcn_mfma_f32_16x16x32_f16(bb, bb, accQB, 0,0,0);
            }
            int j = tl*16 + m16;
            if (quad == 0) { stSB[j] = accSB[0]; stSA[j] = accSA[0]; }
            if (quad == (m16 >> 2)) {
                int r = m16 & 3;
                stG[j] = accG[r]; stQA[j] = accQA[r]; stQB[j] = accQB[r];
            }
        }
    }
    __syncthreads();

    {   // per-j (inv, -mu*inv)
        int j = tid;
        float2 v; v.x = 0.f; v.y = 0.f;
        if (j >= 1) {
            float sa, qa;
            if (i >= 1) {
                sa = saqa[0] + saqa[1] + saqa[2] + saqa[3];
                qa = saqa[4] + saqa[5] + saqa[6] + saqa[7];
            } else {
                sa = stSA[j]; qa = stQA[j];
            }
            float sb = stSB[j], qb2 = stQB[j], g = stG[j];
            float mu  = (sa + sb) * (1.0f/256.0f);
            float var = (qa + qb2 + 2.f*g) * (1.0f/256.0f) - mu*mu;
            float inv = rsqrtf(var + 1e-5f);
            v.x = inv; v.y = -mu*inv;
        }
        st[j] = v;
    }
    __syncthreads();

    // ---- phase B: logits MFMA ----
    f32x4 acc[4] = {};
    float2 sv[4];
    #pragma unroll
    for (int tt = 0; tt < 4; tt++)
        sv[tt] = st[(wave*4 + tt)*16 + m16];

    if (i >= 1) {
        #pragma unroll
        for (int ks = 0; ks < 8; ks++) {
            int k = ks*32 + quad*8;
            float4 a0 = *(const float4*)&aL[k], a1 = *(const float4*)&aL[k+4];
            float4 g0 = *(const float4*)&gL[k], g1 = *(const float4*)&gL[k+4];
            float4 b0 = *(const float4*)&bL[k], b1 = *(const float4*)&bL[k+4];
            half8 bf = *(const half8*)&mfg[(ks*64 + lane) << 3];
            float aa[8] = {a0.x,a0.y,a0.z,a0.w,a1.x,a1.y,a1.z,a1.w};
            float ga[8] = {g0.x,g0.y,g0.z,g0.w,g1.x,g1.y,g1.z,g1.w};
            float be[8] = {b0.x,b0.y,b0.z,b0.w,b1.x,b1.y,b1.z,b1.w};
            #pragma unroll
            for (int tt = 0; tt < 4; tt++) {
                half8 bp = *(const half8*)&bpj[(((wave*4 + tt)*8 + ks)*64 + lane) << 3];
                half8 af;
                #pragma unroll
                for (int e = 0; e < 8; e++) {
                    float c = (float)bp[e] + aa[e];
                    float w = fmaf(fmaf(c, sv[tt].x, sv[tt].y), ga[e], be[e]);
                    af[e] = (_Float16)fmaxf(w, 0.f);
                }
                acc[tt] = __builtin_amdgcn_mfma_f32_16x16x32_f16(af, bf, acc[tt], 0,0,0);
            }
        }
    } else {
        #pragma unroll
        for (int ks = 0; ks < 8; ks++) {
            int k = ks*32 + quad*8;
            float4 g0 = *(const float4*)&gL[k], g1 = *(const float4*)&gL[k+4];
            float4 b0 = *(const float4*)&bL[k], b1 = *(const float4*)&bL[k+4];
            half8 bf = *(const half8*)&mfg[(ks*64 + lane) << 3];
            float ga[8] = {g0.x,g0.y,g0.z,g0.w,g1.x,g1.y,g1.z,g1.w};
            float be[8] = {b0.x,b0.y,b0.z,b0.w,b1.x,b1.y,b1.z,b1.w};
            #pragma unroll
            for (int tt = 0; tt < 4; tt++) {
                int idx = ((((wave*4 + tt)*8 + ks)*64 + lane) << 3);
                half8 bp = *(const half8*)&bpj[idx];
                half8 ap = *(const half8*)&apj[idx];
                half8 af;
                #pragma unroll
                for (int e = 0; e < 8; e++) {
                    float c = (float)ap[e] + (float)bp[e];
                    float w = fmaf(fmaf(c, sv[tt].x, sv[tt].y), ga[e], be[e]);
                    af[e] = (_Float16)fmaxf(w, 0.f);
                }
                acc[tt] = __builtin_amdgcn_mfma_f32_16x16x32_f16(af, bf, acc[tt], 0,0,0);
            }
        }
    }

    if (m16 < 8) {
        float basev = baseh[m16];
        #pragma unroll
        for (int tt = 0; tt < 4; tt++)
            #pragma unroll
            for (int r = 0; r < 4; r++) {
                int jr = (wave*4 + tt)*16 + quad*4 + r;
                float val = basev + klds[m16*256 + jr];
                val += (jr == 0) ? -1e9f : acc[tt][r];
                PL[m16*PLS + jr] = val;
            }
    }
    __syncthreads();

    // ---- softmax ----
    {
        int h = tid >> 5, sg = tid & 31;
        float mv = -INFINITY;
        #pragma unroll
        for (int r = 0; r < 8; r++) mv = fmaxf(mv, PL[h*PLS + sg + r*32]);
        #pragma unroll
        for (int off = 16; off >= 1; off >>= 1)
            mv = fmaxf(mv, __shfl_xor(mv, off, 64));
        if (sg == 0) mxs[h] = mv;
    }
    __syncthreads();
    float p[8];
    #pragma unroll
    for (int h = 0; h < 8; h++) p[h] = expf(PL[h*PLS + tid] - mxs[h]);
    __syncthreads();
    #pragma unroll
    for (int h = 0; h < 8; h++) PL[h*PLS + tid] = p[h];
    __syncthreads();
    {
        int h = tid >> 5, sg = tid & 31;
        float sv2 = 0.f;
        #pragma unroll
        for (int r = 0; r < 8; r++) sv2 += PL[h*PLS + sg + r*32];
        #pragma unroll
        for (int off = 16; off >= 1; off >>= 1)
            sv2 += __shfl_xor(sv2, off, 64);
        if (sg == 0) sms[h] = sv2;
    }
    __syncthreads();

    // ---- attn out ----
    float* attnOut = out + 262144;
    #pragma unroll
    for (int h = 0; h < 8; h++)
        attnOut[((b*8+h)*256 + i)*256 + tid] = p[h] / sms[h];

    // ---- ctx via MFMA: A rows = heads of p, B = VTF frags ----
    {
        f32x4 cacc[4] = {};
        int ct0 = wave*4;
        #pragma unroll
        for (int js = 0; js < 8; js++) {
            half8 af;
            if (m16 < 8) {
                float4 p0 = *(const float4*)&PL[m16*PLS + js*32 + quad*8];
                float4 p1 = *(const float4*)&PL[m16*PLS + js*32 + quad*8 + 4];
                af = cvt8(p0, p1);
            } else af = z8;
            #pragma unroll
            for (int cl = 0; cl < 4; cl++) {
                half8 bf = *(const half8*)&vtf[(((ct0+cl)*8 + js)*64 + lane) << 3];
                cacc[cl] = __builtin_amdgcn_mfma_f32_16x16x32_f16(af, bf, cacc[cl], 0,0,0);
            }
        }
        #pragma unroll
        for (int cl = 0; cl < 4; cl++) {
            int ct = ct0 + cl;
            int h = ct >> 1;
            if (quad == (h >> 2)) {
                float rs = 1.0f / sms[h];
                out[(b*256 + i)*256 + ct*16 + m16] = cacc[cl][h & 3] * rs;
            }
        }
    }
}

// ---------------------------------------------------------------------------
extern "C" void kernel_launch(void* const* d_in, const int* in_sizes, int n_in,
                              void* d_out, int out_size, void* d_ws, size_t ws_size,
                              hipStream_t stream)
{
    const float* desc = (const float*)d_in[0];
    const float* nve  = (const float*)d_in[1];
    const float* qW   = (const float*)d_in[2];
    const float* qb   = (const float*)d_in[3];
    const float* kW   = (const float*)d_in[4];
    const float* kb   = (const float*)d_in[5];
    const float* vW   = (const float*)d_in[6];
    const float* vb   = (const float*)d_in[7];
    const float* eW1  = (const float*)d_in[8];
    const float* eb1  = (const float*)d_in[9];
    const float* ln_g = (const float*)d_in[10];
    const float* ln_b = (const float*)d_in[11];
    const float* eW2  = (const float*)d_in[12];
    const float* eb2  = (const float*)d_in[13];
    const float* aW   = (const float*)d_in[14];
    const float* ab   = (const float*)d_in[15];
    float* ws  = (float*)d_ws;
    float* out = (float*)d_out;

    k1<<<dim3(209), 256, 0, stream>>>(desc, nve, qW, qb, kW, kb, vW, vb,
                                      eW1, eb1, eW2, eb2, aW, ws);
    k3<<<dim3(256, 4), 256, 0, stream>>>(ln_g, ln_b, ab, ws, out);
}